// Round 8
// baseline (2056.669 us; speedup 1.0000x reference)
//
#include <hip/hip_runtime.h>
#include <cstdint>
#include <cmath>

typedef __attribute__((ext_vector_type(8))) short short8;
typedef __attribute__((ext_vector_type(4))) float floatx4;

#define DEV static __device__ __forceinline__

DEV float bf2f(uint16_t u) {
    union { uint32_t i; float f; } v; v.i = ((uint32_t)u) << 16; return v.f;
}
DEV uint16_t f2bf(float f) {
    union { float f; uint32_t i; } v; v.f = f;
    uint32_t r = (v.i + 0x7FFFu + ((v.i >> 16) & 1u)) >> 16;
    return (uint16_t)r;
}
DEV float swishf(float x) { return x / (1.f + __expf(-x)); }
DEV float geluf(float x) {
    const float c = 0.7978845608028654f;
    float t = tanhf(c * (x + 0.044715f * x * x * x));
    return 0.5f * x * (1.f + t);
}

// W packing: per 32-K chunk, layout [n(256)][32] contiguous -> a wave's B-fragment
// is a contiguous 1 KB region, coalesced dwordx4 loads straight from L2.
#define CHUNK_E 8192
#define MAT_E   65536   // 8 chunks

// ---- transpose+convert W + zero barrier counters ----
struct TArg { const float* src[15]; };

__global__ __launch_bounds__(256) void tpose_k(TArg ta, uint16_t* __restrict__ arena,
                                               unsigned* __restrict__ bar) {
    int z = blockIdx.z;
    int t = threadIdx.x;
    const float* src; uint16_t* dst;
    if (z == 0) {
        if (blockIdx.x == 0 && blockIdx.y == 0) {
#pragma unroll
            for (int j = 0; j < 3; ++j) bar[j * 256 + t] = 0;   // 768 counters
        }
        if (blockIdx.y) return;
        src = ta.src[0]; dst = arena;                            // w_enc [32,256]
    } else if (z <= 39) {
        int q = z - 1; int ti = q / 3, s = q % 3;
        src = ta.src[1 + ti] + (size_t)s * 65536;
        dst = arena + CHUNK_E + (size_t)(ti * 3 + s) * MAT_E;
    } else {
        src = ta.src[14]; dst = arena + CHUNK_E + (size_t)39 * MAT_E;   // hw1
    }
    int k0 = blockIdx.y << 5;
    int n0 = blockIdx.x << 6;
    __shared__ __align__(16) uint16_t tile[32][72];
    {
        int r = t >> 3, c = (t & 7) << 3;
        const float* s0 = src + (size_t)(k0 + r) * 256 + n0 + c;
        float4 f0 = *(const float4*)s0;
        float4 f1 = *(const float4*)(s0 + 4);
        tile[r][c + 0] = f2bf(f0.x); tile[r][c + 1] = f2bf(f0.y);
        tile[r][c + 2] = f2bf(f0.z); tile[r][c + 3] = f2bf(f0.w);
        tile[r][c + 4] = f2bf(f1.x); tile[r][c + 5] = f2bf(f1.y);
        tile[r][c + 6] = f2bf(f1.z); tile[r][c + 7] = f2bf(f1.w);
    }
    __syncthreads();
    {
        int n = t >> 2, c = (t & 3) << 3;
        uint16_t tmp[8];
#pragma unroll
        for (int j = 0; j < 8; ++j) tmp[j] = tile[c + j][n];
        *(uint4*)&dst[(size_t)(k0 >> 5) * CHUNK_E + (size_t)(n0 + n) * 32 + c] = *(uint4*)tmp;
    }
}

// ---------------- mega kernel (regular launch, sibling barriers) ----------------
union LdsU {
    struct { uint16_t QS[256][40]; uint16_t Ks[256][40]; uint16_t Vt[32][264]; } a;  // 57856 B
    float rowsum[4][32];
    float w2[8192];
};

struct MegaArgs {
    const float* action; const float* obs;
    const uint16_t* wt;
    uint16_t *actb, *obsb, *xb, *bq, *bk, *bv, *bg, *brg;
    float *xf;
    unsigned* bar;
    const float *ln0, *gns1, *gnb1, *ln1, *gns2, *gnb2, *ln2, *ln3, *hb1, *hln, *hw2, *hb2;
    float* outp;
    float l2g[8];
};

// 8-sibling barrier; fresh counter per barrier point (no reset/generation logic).
DEV void batch_bar(unsigned* p) {
    __syncthreads();
    if (threadIdx.x == 0) {
        __threadfence();   // agent-scope release: wb XCD L2 so siblings see our stores
        __hip_atomic_fetch_add(p, 1u, __ATOMIC_RELAXED, __HIP_MEMORY_SCOPE_AGENT);
        while (__hip_atomic_load(p, __ATOMIC_RELAXED, __HIP_MEMORY_SCOPE_AGENT) < 8u)
            __builtin_amdgcn_s_sleep(4);
    }
    __syncthreads();
    __threadfence();       // agent-scope acquire: invalidate L1/L2 before reading siblings
}

enum { EP_NONE = 0, EP_GELU_RMS = 1, EP_RESID_RMS = 2, EP_STASH = 3, EP_SWIMUL = 4 };

// 32-row x 256-col GEMM tile, zero-LDS main loop. Block-local rows.
template<int EPI, int K>
DEV void gemm_dev(int m0, const uint16_t* __restrict__ A, const uint16_t* __restrict__ Wt,
                  uint16_t* __restrict__ O, const float* __restrict__ bias,
                  const float* __restrict__ resid, const float* __restrict__ lnw,
                  float* __restrict__ xout, float (&rowsum)[4][32], float* sv)
{
    const int t = threadIdx.x;
    const int w = t >> 6, lane = t & 63, l16 = lane & 15, lg = lane >> 4;
    constexpr int NC = K / 32;

    floatx4 acc[2][4];
#pragma unroll
    for (int i = 0; i < 2; ++i)
#pragma unroll
        for (int j = 0; j < 4; ++j) acc[i][j] = (floatx4){0.f, 0.f, 0.f, 0.f};

#pragma unroll
    for (int kc = 0; kc < NC; ++kc) {
        short8 aF[2], bF[4];
#pragma unroll
        for (int rt = 0; rt < 2; ++rt)
            aF[rt] = *(const short8*)(A + (size_t)(m0 + (rt << 4) + l16) * K +
                                      (kc << 5) + (lg << 3));
#pragma unroll
        for (int ct = 0; ct < 4; ++ct)
            bF[ct] = *(const short8*)(Wt + (size_t)kc * CHUNK_E +
                                      (size_t)((w << 6) + (ct << 4) + l16) * 32 + (lg << 3));
#pragma unroll
        for (int rt = 0; rt < 2; ++rt)
#pragma unroll
            for (int ct = 0; ct < 4; ++ct)
                acc[rt][ct] = __builtin_amdgcn_mfma_f32_16x16x32_bf16(
                    aF[rt], bF[ct], acc[rt][ct], 0, 0, 0);
    }

    if (EPI == EP_STASH) {
#pragma unroll
        for (int rt = 0; rt < 2; ++rt)
#pragma unroll
            for (int ct = 0; ct < 4; ++ct)
#pragma unroll
                for (int r = 0; r < 4; ++r)
                    sv[((rt << 2) + ct) * 4 + r] = acc[rt][ct][r];
        return;
    }

    float v[2][4][4];
#pragma unroll
    for (int rt = 0; rt < 2; ++rt)
#pragma unroll
        for (int ct = 0; ct < 4; ++ct)
#pragma unroll
            for (int r = 0; r < 4; ++r) {
                int row = (rt << 4) + (lg << 2) + r;
                int col = (w << 6) + (ct << 4) + l16;
                size_t idx = (size_t)(m0 + row) * 256 + col;
                float x = acc[rt][ct][r];
                if (EPI == EP_GELU_RMS) { if (bias) x += bias[col]; x = geluf(x); }
                if (EPI == EP_RESID_RMS) x += resid[idx];
                if (EPI == EP_SWIMUL) x *= swishf(sv[((rt << 2) + ct) * 4 + r]);
                v[rt][ct][r] = x;
            }

    if (EPI == EP_GELU_RMS || EPI == EP_RESID_RMS) {
#pragma unroll
        for (int rt = 0; rt < 2; ++rt)
#pragma unroll
            for (int r = 0; r < 4; ++r) {
                float p = 0.f;
#pragma unroll
                for (int ct = 0; ct < 4; ++ct) p += v[rt][ct][r] * v[rt][ct][r];
                p += __shfl_xor(p, 1, 64); p += __shfl_xor(p, 2, 64);
                p += __shfl_xor(p, 4, 64); p += __shfl_xor(p, 8, 64);
                int row = (rt << 4) + (lg << 2) + r;
                if (l16 == 0) rowsum[w][row] = p;
            }
        __syncthreads();
#pragma unroll
        for (int rt = 0; rt < 2; ++rt)
#pragma unroll
            for (int r = 0; r < 4; ++r) {
                int row = (rt << 4) + (lg << 2) + r;
                float tot = rowsum[0][row] + rowsum[1][row] + rowsum[2][row] + rowsum[3][row];
                float rn = rsqrtf(tot * (1.f / 256.f) + 1e-6f);
#pragma unroll
                for (int ct = 0; ct < 4; ++ct) {
                    int col = (w << 6) + (ct << 4) + l16;
                    size_t idx = (size_t)(m0 + row) * 256 + col;
                    float o = v[rt][ct][r] * rn * lnw[col];
                    O[idx] = f2bf(o);
                    if (xout) xout[idx] = o;
                }
            }
        __syncthreads();
    } else {
#pragma unroll
        for (int rt = 0; rt < 2; ++rt)
#pragma unroll
            for (int ct = 0; ct < 4; ++ct)
#pragma unroll
                for (int r = 0; r < 4; ++r) {
                    int row = (rt << 4) + (lg << 2) + r;
                    int col = (w << 6) + (ct << 4) + l16;
                    O[(size_t)(m0 + row) * 256 + col] = f2bf(v[rt][ct][r]);
                }
    }
}

DEV void attn_dev(LdsU& L, int b, int h, const uint16_t* __restrict__ q,
                  const uint16_t* __restrict__ kbuf, const uint16_t* __restrict__ vbuf,
                  const uint16_t* __restrict__ g, const float* __restrict__ gns,
                  const float* __restrict__ gnb, uint16_t* __restrict__ out, float l2g)
{
    const int t = threadIdx.x, w = t >> 6, lane = t & 63, l16 = lane & 15, lg = lane >> 4;
    const size_t base = ((size_t)b * 256) * 256 + (size_t)h * 32;

    {
        const uint4* qr = (const uint4*)(q + base + (size_t)t * 256);
        *(uint4*)&L.a.QS[t][0] = qr[0]; *(uint4*)&L.a.QS[t][8] = qr[1];
        *(uint4*)&L.a.QS[t][16] = qr[2]; *(uint4*)&L.a.QS[t][24] = qr[3];
        const uint4* kr = (const uint4*)(kbuf + base + (size_t)t * 256);
        *(uint4*)&L.a.Ks[t][0] = kr[0]; *(uint4*)&L.a.Ks[t][8] = kr[1];
        *(uint4*)&L.a.Ks[t][16] = kr[2]; *(uint4*)&L.a.Ks[t][24] = kr[3];
        union { uint4 v4[4]; uint16_t u[32]; } vv;
        const uint4* vr = (const uint4*)(vbuf + base + (size_t)t * 256);
        vv.v4[0] = vr[0]; vv.v4[1] = vr[1]; vv.v4[2] = vr[2]; vv.v4[3] = vr[3];
#pragma unroll
        for (int d = 0; d < 32; ++d) L.a.Vt[d][t] = vv.u[d];
    }
    __syncthreads();

    short8 qF[4];
#pragma unroll
    for (int rt = 0; rt < 4; ++rt)
        qF[rt] = *(const short8*)&L.a.QS[(w << 6) + (rt << 4) + l16][lg << 3];

    floatx4 racc[4][2];
#pragma unroll
    for (int i = 0; i < 4; ++i) { racc[i][0] = (floatx4){0,0,0,0}; racc[i][1] = (floatx4){0,0,0,0}; }

    const float invsq = 0.17677669529663687f;
    for (int jt = 0; jt < 8; ++jt) {
        const int j0 = jt << 5;
        floatx4 sacc[4][2];
#pragma unroll
        for (int i = 0; i < 4; ++i) { sacc[i][0] = (floatx4){0,0,0,0}; sacc[i][1] = (floatx4){0,0,0,0}; }
        short8 kF[2];
#pragma unroll
        for (int ct = 0; ct < 2; ++ct)
            kF[ct] = *(const short8*)&L.a.Ks[j0 + (ct << 4) + l16][lg << 3];
#pragma unroll
        for (int rt = 0; rt < 4; ++rt)
#pragma unroll
            for (int ct = 0; ct < 2; ++ct)
                sacc[rt][ct] = __builtin_amdgcn_mfma_f32_16x16x32_bf16(
                    qF[rt], kF[ct], sacc[rt][ct], 0, 0, 0);
#pragma unroll
        for (int rt = 0; rt < 4; ++rt)
#pragma unroll
            for (int ct = 0; ct < 2; ++ct)
#pragma unroll
                for (int r = 0; r < 4; ++r) {
                    int row = (rt << 4) + (lg << 2) + r;
                    int i = (w << 6) + row;
                    int j = j0 + (ct << 4) + l16;
                    float svv = 0.f;
                    if (i >= j)
                        svv = sacc[rt][ct][r] * invsq *
                              exp2f((float)((i >> 3) - (j >> 3)) * l2g);
                    L.a.QS[(w << 6) + row][(ct << 4) + l16] = f2bf(svv);
                }
        short8 vF[2];
#pragma unroll
        for (int ct = 0; ct < 2; ++ct)
            vF[ct] = *(const short8*)&L.a.Vt[(ct << 4) + l16][j0 + (lg << 3)];
#pragma unroll
        for (int rt = 0; rt < 4; ++rt) {
            short8 sF = *(const short8*)&L.a.QS[(w << 6) + (rt << 4) + l16][lg << 3];
#pragma unroll
            for (int ct = 0; ct < 2; ++ct)
                racc[rt][ct] = __builtin_amdgcn_mfma_f32_16x16x32_bf16(
                    sF, vF[ct], racc[rt][ct], 0, 0, 0);
        }
    }

#pragma unroll
    for (int rt = 0; rt < 4; ++rt)
#pragma unroll
        for (int r = 0; r < 4; ++r) {
            float v0 = racc[rt][0][r], v1 = racc[rt][1][r];
            float s1 = v0 + v1, s2 = v0 * v0 + v1 * v1;
            s1 += __shfl_xor(s1, 1, 64); s2 += __shfl_xor(s2, 1, 64);
            s1 += __shfl_xor(s1, 2, 64); s2 += __shfl_xor(s2, 2, 64);
            s1 += __shfl_xor(s1, 4, 64); s2 += __shfl_xor(s2, 4, 64);
            s1 += __shfl_xor(s1, 8, 64); s2 += __shfl_xor(s2, 8, 64);
            float mu = s1 * (1.f / 32.f);
            float var = s2 * (1.f / 32.f) - mu * mu;
            float rstd = rsqrtf(var + 1e-5f);
            int srow = (w << 6) + (rt << 4) + (lg << 2) + r;
            size_t obase = ((size_t)b * 256 + srow) * 256 + (size_t)h * 32;
#pragma unroll
            for (int ct = 0; ct < 2; ++ct) {
                int d = (ct << 4) + l16;
                float x = ct ? v1 : v0;
                float y = (x - mu) * rstd * gns[h * 32 + d] + gnb[h * 32 + d];
                float gv = swishf(bf2f(g[obase + d]));
                out[obase + d] = f2bf(y * gv);
            }
        }
}

__global__ __launch_bounds__(256, 2) void mega_k(MegaArgs ma)
{
    __shared__ __align__(16) LdsU L;
    const int t = threadIdx.x;
    const int blk = blockIdx.x;
    const int b = blk >> 3, h = blk & 7;       // siblings of batch b: blk 8b..8b+7
    const int m0 = blk * 32;                   // rows owned = batch b, rows h*32..+31
    unsigned* bar = ma.bar + b * 12;

    const uint16_t* wt = ma.wt;
    auto WTp = [&](int ti, int s) { return wt + CHUNK_E + (size_t)(ti * 3 + s) * MAT_E; };
    const uint16_t* wtenc = wt;
    const uint16_t* hw1t  = wt + CHUNK_E + (size_t)39 * MAT_E;

    // ---- S0: convert action + obs rows (block-local), encoder, qkv1(layer 0) ----
    {
        int r = t >> 3, c = (t & 7) << 2;
        float4 f = *(const float4*)(ma.action + (size_t)(m0 + r) * 32 + c);
        uint16_t tmp[4] = { f2bf(f.x), f2bf(f.y), f2bf(f.z), f2bf(f.w) };
        *(uint2*)(ma.actb + (size_t)(m0 + r) * 32 + c) = *(uint2*)tmp;
    }
    {
        const float4* ob = (const float4*)ma.obs + (size_t)m0 * 64;
        uint2* od = (uint2*)ma.obsb + (size_t)m0 * 64;
#pragma unroll
        for (int j = 0; j < 8; ++j) {
            float4 f = ob[j * 256 + t];
            uint16_t tmp[4] = { f2bf(f.x), f2bf(f.y), f2bf(f.z), f2bf(f.w) };
            od[j * 256 + t] = *(uint2*)tmp;
        }
    }
    __syncthreads();
    gemm_dev<EP_GELU_RMS, 32>(m0, ma.actb, wtenc, ma.xb, nullptr, nullptr, ma.ln0,
                              ma.xf, L.rowsum, nullptr);
    gemm_dev<EP_NONE, 256>(m0, ma.xb, WTp(0, 0), ma.bq, nullptr, nullptr, nullptr, nullptr, L.rowsum, nullptr);
    gemm_dev<EP_NONE, 256>(m0, ma.xb, WTp(1, 0), ma.bk, nullptr, nullptr, nullptr, nullptr, L.rowsum, nullptr);
    gemm_dev<EP_NONE, 256>(m0, ma.xb, WTp(2, 0), ma.bv, nullptr, nullptr, nullptr, nullptr, L.rowsum, nullptr);
    gemm_dev<EP_NONE, 256>(m0, ma.xb, WTp(3, 0), ma.bg, nullptr, nullptr, nullptr, nullptr, L.rowsum, nullptr);

    for (int b3 = 0; b3 < 3; ++b3) {
        batch_bar(bar + b3 * 4 + 0);   // siblings' qkv1 ready
        attn_dev(L, b, h, ma.bq, ma.bk, ma.bv, ma.bg,
                 ma.gns1 + b3 * 256, ma.gnb1 + b3 * 256, ma.brg, ma.l2g[h]);
        batch_bar(bar + b3 * 4 + 1);   // siblings' attn1 column-slices ready
        gemm_dev<EP_RESID_RMS, 256>(m0, ma.brg, WTp(4, b3), ma.xb, nullptr, ma.xf,
                                    ma.ln1 + b3 * 256, ma.xf, L.rowsum, nullptr);
        // qkv2: row-split, needs only own xb/obsb rows (block-local)
        gemm_dev<EP_NONE, 256>(m0, ma.xb,   WTp(6, b3), ma.bk, nullptr, nullptr, nullptr, nullptr, L.rowsum, nullptr);
        gemm_dev<EP_NONE, 256>(m0, ma.xb,   WTp(7, b3), ma.bv, nullptr, nullptr, nullptr, nullptr, L.rowsum, nullptr);
        gemm_dev<EP_NONE, 256>(m0, ma.obsb, WTp(5, b3), ma.bq, nullptr, nullptr, nullptr, nullptr, L.rowsum, nullptr);
        gemm_dev<EP_NONE, 256>(m0, ma.obsb, WTp(8, b3), ma.bg, nullptr, nullptr, nullptr, nullptr, L.rowsum, nullptr);
        batch_bar(bar + b3 * 4 + 2);   // siblings' qkv2 ready
        attn_dev(L, b, h, ma.bq, ma.bk, ma.bv, ma.bg,
                 ma.gns2 + b3 * 256, ma.gnb2 + b3 * 256, ma.brg, ma.l2g[h]);
        batch_bar(bar + b3 * 4 + 3);   // siblings' attn2 ready
        gemm_dev<EP_RESID_RMS, 256>(m0, ma.brg, WTp(9, b3), ma.xb, nullptr, ma.obs,
                                    ma.ln2 + b3 * 256, ma.xf, L.rowsum, nullptr);
        {
            float sv[32];
            gemm_dev<EP_STASH, 256>(m0, ma.xb, WTp(10, b3), nullptr, nullptr, nullptr,
                                    nullptr, nullptr, L.rowsum, sv);
            gemm_dev<EP_SWIMUL, 256>(m0, ma.xb, WTp(11, b3), ma.bk, nullptr, nullptr,
                                     nullptr, nullptr, L.rowsum, sv);
        }
        __syncthreads();
        gemm_dev<EP_RESID_RMS, 256>(m0, ma.bk, WTp(12, b3), ma.xb, nullptr, ma.xf,
                                    ma.ln3 + b3 * 256, ma.xf, L.rowsum, nullptr);
        if (b3 < 2) {
            gemm_dev<EP_NONE, 256>(m0, ma.xb, WTp(0, b3 + 1), ma.bq, nullptr, nullptr, nullptr, nullptr, L.rowsum, nullptr);
            gemm_dev<EP_NONE, 256>(m0, ma.xb, WTp(1, b3 + 1), ma.bk, nullptr, nullptr, nullptr, nullptr, L.rowsum, nullptr);
            gemm_dev<EP_NONE, 256>(m0, ma.xb, WTp(2, b3 + 1), ma.bv, nullptr, nullptr, nullptr, nullptr, L.rowsum, nullptr);
            gemm_dev<EP_NONE, 256>(m0, ma.xb, WTp(3, b3 + 1), ma.bg, nullptr, nullptr, nullptr, nullptr, L.rowsum, nullptr);
        }
    }

    // ---- head: h = rms(gelu(x@hw1 + hb1)); out = h@hw2 + hb2 (all block-local) ----
    gemm_dev<EP_GELU_RMS, 256>(m0, ma.xb, hw1t, ma.bq, ma.hb1, nullptr, ma.hln,
                               nullptr, L.rowsum, nullptr);
    __syncthreads();
#pragma unroll
    for (int j = 0; j < 32; ++j) L.w2[j * 256 + t] = ma.hw2[j * 256 + t];
    __syncthreads();
    {
        int n = t & 31, rs = t >> 5;
#pragma unroll
        for (int rr = 0; rr < 4; ++rr) {
            int row = m0 + (rr << 3) + rs;
            float a0 = ma.hb2[n];
#pragma unroll 8
            for (int kk = 0; kk < 256; ++kk)
                a0 += bf2f(ma.bq[(size_t)row * 256 + kk]) * L.w2[kk * 32 + n];
            ma.outp[(size_t)row * 32 + n] = a0;
        }
    }
}

// ---------------- host ----------------
extern "C" void kernel_launch(void* const* d_in, const int* in_sizes, int n_in,
                              void* d_out, int out_size, void* d_ws, size_t ws_size,
                              hipStream_t stream)
{
    const float* action = (const float*)d_in[0];
    const float* obs    = (const float*)d_in[1];
    const float* w_enc  = (const float*)d_in[2];
    const float* ln0    = (const float*)d_in[3];
    const float* wq1 = (const float*)d_in[4];
    const float* wk1 = (const float*)d_in[5];
    const float* wv1 = (const float*)d_in[6];
    const float* wg1 = (const float*)d_in[7];
    const float* wo1 = (const float*)d_in[8];
    const float* gns1 = (const float*)d_in[9];
    const float* gnb1 = (const float*)d_in[10];
    const float* ln1  = (const float*)d_in[11];
    const float* wq2 = (const float*)d_in[12];
    const float* wk2 = (const float*)d_in[13];
    const float* wv2 = (const float*)d_in[14];
    const float* wg2 = (const float*)d_in[15];
    const float* wo2 = (const float*)d_in[16];
    const float* gns2 = (const float*)d_in[17];
    const float* gnb2 = (const float*)d_in[18];
    const float* ln2  = (const float*)d_in[19];
    const float* swgp = (const float*)d_in[20];
    const float* sw1p = (const float*)d_in[21];
    const float* sw2p = (const float*)d_in[22];
    const float* ln3  = (const float*)d_in[23];
    const float* hw1  = (const float*)d_in[24];
    const float* hb1  = (const float*)d_in[25];
    const float* hln  = (const float*)d_in[26];
    const float* hw2  = (const float*)d_in[27];
    const float* hb2  = (const float*)d_in[28];

    char* ws = (char*)d_ws;
    uint16_t* wt   = (uint16_t*)(ws + 0);
    uint16_t* actb = (uint16_t*)(ws + 6291456);
    uint16_t* obsb = (uint16_t*)(ws + 7340032);
    float*    xf   = (float*)   (ws + 15728640);
    uint16_t* xb   = (uint16_t*)(ws + 32505856);
    uint16_t* bq   = (uint16_t*)(ws + 40894464);
    uint16_t* bk   = (uint16_t*)(ws + 49283072);
    uint16_t* bv   = (uint16_t*)(ws + 57671680);
    uint16_t* bg   = (uint16_t*)(ws + 66060288);
    uint16_t* brg  = (uint16_t*)(ws + 74448896);
    unsigned* bar  = (unsigned*)(ws + 82837504);   // 768 counters (3 KB)

    TArg ta;
    ta.src[0] = w_enc;
    ta.src[1] = wq1;  ta.src[2] = wk1;  ta.src[3] = wv1;  ta.src[4] = wg1;  ta.src[5] = wo1;
    ta.src[6] = wq2;  ta.src[7] = wk2;  ta.src[8] = wv2;  ta.src[9] = wg2;  ta.src[10] = wo2;
    ta.src[11] = swgp; ta.src[12] = sw1p; ta.src[13] = sw2p; ta.src[14] = hw1;
    tpose_k<<<dim3(4, 8, 41), 256, 0, stream>>>(ta, wt, bar);

    MegaArgs ma;
    ma.action = action; ma.obs = obs; ma.wt = wt;
    ma.actb = actb; ma.obsb = obsb; ma.xb = xb;
    ma.bq = bq; ma.bk = bk; ma.bv = bv; ma.bg = bg; ma.brg = brg;
    ma.xf = xf; ma.bar = bar;
    ma.ln0 = ln0; ma.gns1 = gns1; ma.gnb1 = gnb1; ma.ln1 = ln1;
    ma.gns2 = gns2; ma.gnb2 = gnb2; ma.ln2 = ln2; ma.ln3 = ln3;
    ma.hb1 = hb1; ma.hln = hln; ma.hw2 = hw2; ma.hb2 = hb2;
    ma.outp = (float*)d_out;
    {
        const double a = log(1.0 / 32.0), bb = log(1.0 / 512.0);
        for (int hh = 0; hh < 8; ++hh) {
            double lg = a + (bb - a) * hh / 7.0;
            double gam = 1.0 - exp(lg);
            ma.l2g[hh] = (float)(log(gam) / log(2.0));
        }
    }
    mega_k<<<512, 256, 0, stream>>>(ma);
}

// Round 9
// 740.791 us; speedup vs baseline: 2.7763x; 2.7763x over previous
//
#include <hip/hip_runtime.h>
#include <cstdint>
#include <cmath>

typedef __attribute__((ext_vector_type(8))) short short8;
typedef __attribute__((ext_vector_type(4))) float floatx4;

#define DEV static __device__ __forceinline__

DEV float bf2f(uint16_t u) {
    union { uint32_t i; float f; } v; v.i = ((uint32_t)u) << 16; return v.f;
}
DEV uint16_t f2bf(float f) {
    union { float f; uint32_t i; } v; v.f = f;
    uint32_t r = (v.i + 0x7FFFu + ((v.i >> 16) & 1u)) >> 16;
    return (uint16_t)r;
}
DEV float swishf(float x) { return x / (1.f + __expf(-x)); }
DEV float geluf(float x) {
    const float c = 0.7978845608028654f;
    float t = tanhf(c * (x + 0.044715f * x * x * x));
    return 0.5f * x * (1.f + t);
}

// W packing: per 32-K chunk, layout [n(256)][32] contiguous -> a wave's B-fragment
// is a contiguous 1 KB region, coalesced dwordx4 loads straight from L2.
#define CHUNK_E 8192
#define MAT_E   65536   // 8 chunks

// ---- transpose+convert: W[K,N=256] fp32 -> packed chunks [kc][n][32] bf16 ----
struct TArg { const float* src[15]; };

__global__ __launch_bounds__(256) void tpose_k(TArg ta, uint16_t* __restrict__ arena) {
    int z = blockIdx.z;
    const float* src; uint16_t* dst;
    if (z == 0) {
        if (blockIdx.y) return;
        src = ta.src[0]; dst = arena;                            // w_enc [32,256]
    } else if (z <= 39) {
        int q = z - 1; int ti = q / 3, s = q % 3;
        src = ta.src[1 + ti] + (size_t)s * 65536;
        dst = arena + CHUNK_E + (size_t)(ti * 3 + s) * MAT_E;
    } else {
        src = ta.src[14]; dst = arena + CHUNK_E + (size_t)39 * MAT_E;   // hw1
    }
    int k0 = blockIdx.y << 5;
    int n0 = blockIdx.x << 6;
    __shared__ __align__(16) uint16_t tile[32][72];
    int t = threadIdx.x;
    {
        int r = t >> 3, c = (t & 7) << 3;
        const float* s0 = src + (size_t)(k0 + r) * 256 + n0 + c;
        float4 f0 = *(const float4*)s0;
        float4 f1 = *(const float4*)(s0 + 4);
        tile[r][c + 0] = f2bf(f0.x); tile[r][c + 1] = f2bf(f0.y);
        tile[r][c + 2] = f2bf(f0.z); tile[r][c + 3] = f2bf(f0.w);
        tile[r][c + 4] = f2bf(f1.x); tile[r][c + 5] = f2bf(f1.y);
        tile[r][c + 6] = f2bf(f1.z); tile[r][c + 7] = f2bf(f1.w);
    }
    __syncthreads();
    {
        int n = t >> 2, c = (t & 3) << 3;
        uint16_t tmp[8];
#pragma unroll
        for (int j = 0; j < 8; ++j) tmp[j] = tile[c + j][n];
        *(uint4*)&dst[(size_t)(k0 >> 5) * CHUNK_E + (size_t)(n0 + n) * 32 + c] = *(uint4*)tmp;
    }
}

// ---------------- shared pieces ----------------
struct SegArgs {
    const float* action; const float* obs;
    uint16_t *actb, *obsb, *xb, *bq, *bk, *bv, *bg, *brg;
    float *xf;
    const float *ln0, *hb1, *hln, *hw2, *hb2;
    float* outp;
    float l2g[8];
};

enum { EP_NONE = 0, EP_GELU_RMS = 1, EP_RESID_RMS = 2, EP_STASH = 3, EP_SWIMUL = 4 };

// 32-row x 256-col GEMM tile, zero-LDS main loop. Block-local rows.
template<int EPI, int K>
DEV void gemm_dev(int m0, const uint16_t* __restrict__ A, const uint16_t* __restrict__ Wt,
                  uint16_t* __restrict__ O, const float* __restrict__ bias,
                  const float* __restrict__ resid, const float* __restrict__ lnw,
                  float* __restrict__ xout, float (&rowsum)[4][32], float* sv)
{
    const int t = threadIdx.x;
    const int w = t >> 6, lane = t & 63, l16 = lane & 15, lg = lane >> 4;
    constexpr int NC = K / 32;

    floatx4 acc[2][4];
#pragma unroll
    for (int i = 0; i < 2; ++i)
#pragma unroll
        for (int j = 0; j < 4; ++j) acc[i][j] = (floatx4){0.f, 0.f, 0.f, 0.f};

#pragma unroll
    for (int kc = 0; kc < NC; ++kc) {
        short8 aF[2], bF[4];
#pragma unroll
        for (int rt = 0; rt < 2; ++rt)
            aF[rt] = *(const short8*)(A + (size_t)(m0 + (rt << 4) + l16) * K +
                                      (kc << 5) + (lg << 3));
#pragma unroll
        for (int ct = 0; ct < 4; ++ct)
            bF[ct] = *(const short8*)(Wt + (size_t)kc * CHUNK_E +
                                      (size_t)((w << 6) + (ct << 4) + l16) * 32 + (lg << 3));
#pragma unroll
        for (int rt = 0; rt < 2; ++rt)
#pragma unroll
            for (int ct = 0; ct < 4; ++ct)
                acc[rt][ct] = __builtin_amdgcn_mfma_f32_16x16x32_bf16(
                    aF[rt], bF[ct], acc[rt][ct], 0, 0, 0);
    }

    if (EPI == EP_STASH) {
#pragma unroll
        for (int rt = 0; rt < 2; ++rt)
#pragma unroll
            for (int ct = 0; ct < 4; ++ct)
#pragma unroll
                for (int r = 0; r < 4; ++r)
                    sv[((rt << 2) + ct) * 4 + r] = acc[rt][ct][r];
        return;
    }

    float v[2][4][4];
#pragma unroll
    for (int rt = 0; rt < 2; ++rt)
#pragma unroll
        for (int ct = 0; ct < 4; ++ct)
#pragma unroll
            for (int r = 0; r < 4; ++r) {
                int row = (rt << 4) + (lg << 2) + r;
                int col = (w << 6) + (ct << 4) + l16;
                size_t idx = (size_t)(m0 + row) * 256 + col;
                float x = acc[rt][ct][r];
                if (EPI == EP_GELU_RMS) { if (bias) x += bias[col]; x = geluf(x); }
                if (EPI == EP_RESID_RMS) x += resid[idx];
                if (EPI == EP_SWIMUL) x *= swishf(sv[((rt << 2) + ct) * 4 + r]);
                v[rt][ct][r] = x;
            }

    if (EPI == EP_GELU_RMS || EPI == EP_RESID_RMS) {
#pragma unroll
        for (int rt = 0; rt < 2; ++rt)
#pragma unroll
            for (int r = 0; r < 4; ++r) {
                float p = 0.f;
#pragma unroll
                for (int ct = 0; ct < 4; ++ct) p += v[rt][ct][r] * v[rt][ct][r];
                p += __shfl_xor(p, 1, 64); p += __shfl_xor(p, 2, 64);
                p += __shfl_xor(p, 4, 64); p += __shfl_xor(p, 8, 64);
                int row = (rt << 4) + (lg << 2) + r;
                if (l16 == 0) rowsum[w][row] = p;
            }
        __syncthreads();
#pragma unroll
        for (int rt = 0; rt < 2; ++rt)
#pragma unroll
            for (int r = 0; r < 4; ++r) {
                int row = (rt << 4) + (lg << 2) + r;
                float tot = rowsum[0][row] + rowsum[1][row] + rowsum[2][row] + rowsum[3][row];
                float rn = rsqrtf(tot * (1.f / 256.f) + 1e-6f);
#pragma unroll
                for (int ct = 0; ct < 4; ++ct) {
                    int col = (w << 6) + (ct << 4) + l16;
                    size_t idx = (size_t)(m0 + row) * 256 + col;
                    float o = v[rt][ct][r] * rn * lnw[col];
                    O[idx] = f2bf(o);
                    if (xout) xout[idx] = o;
                }
            }
        __syncthreads();
    } else {
#pragma unroll
        for (int rt = 0; rt < 2; ++rt)
#pragma unroll
            for (int ct = 0; ct < 4; ++ct)
#pragma unroll
                for (int r = 0; r < 4; ++r) {
                    int row = (rt << 4) + (lg << 2) + r;
                    int col = (w << 6) + (ct << 4) + l16;
                    O[(size_t)(m0 + row) * 256 + col] = f2bf(v[rt][ct][r]);
                }
    }
}

// ---------------- segment kernels ----------------
// Block blk owns rows blk*32..+31 (batch blk>>3). 512 blocks everywhere.

__global__ __launch_bounds__(256) void seg0_k(SegArgs sa, const uint16_t* __restrict__ wenc,
                                              const uint16_t* __restrict__ wq,
                                              const uint16_t* __restrict__ wk,
                                              const uint16_t* __restrict__ wv,
                                              const uint16_t* __restrict__ wg)
{
    __shared__ float rowsum[4][32];
    const int t = threadIdx.x;
    const int m0 = blockIdx.x * 32;
    {
        int r = t >> 3, c = (t & 7) << 2;
        float4 f = *(const float4*)(sa.action + (size_t)(m0 + r) * 32 + c);
        uint16_t tmp[4] = { f2bf(f.x), f2bf(f.y), f2bf(f.z), f2bf(f.w) };
        *(uint2*)(sa.actb + (size_t)(m0 + r) * 32 + c) = *(uint2*)tmp;
    }
    {
        const float4* ob = (const float4*)sa.obs + (size_t)m0 * 64;
        uint2* od = (uint2*)sa.obsb + (size_t)m0 * 64;
#pragma unroll
        for (int j = 0; j < 8; ++j) {
            float4 f = ob[j * 256 + t];
            uint16_t tmp[4] = { f2bf(f.x), f2bf(f.y), f2bf(f.z), f2bf(f.w) };
            od[j * 256 + t] = *(uint2*)tmp;
        }
    }
    __syncthreads();
    gemm_dev<EP_GELU_RMS, 32>(m0, sa.actb, wenc, sa.xb, nullptr, nullptr, sa.ln0,
                              sa.xf, rowsum, nullptr);
    gemm_dev<EP_NONE, 256>(m0, sa.xb, wq, sa.bq, nullptr, nullptr, nullptr, nullptr, rowsum, nullptr);
    gemm_dev<EP_NONE, 256>(m0, sa.xb, wk, sa.bk, nullptr, nullptr, nullptr, nullptr, rowsum, nullptr);
    gemm_dev<EP_NONE, 256>(m0, sa.xb, wv, sa.bv, nullptr, nullptr, nullptr, nullptr, rowsum, nullptr);
    gemm_dev<EP_NONE, 256>(m0, sa.xb, wg, sa.bg, nullptr, nullptr, nullptr, nullptr, rowsum, nullptr);
}

__global__ __launch_bounds__(256) void attn_k(SegArgs sa, const float* __restrict__ gns,
                                              const float* __restrict__ gnb)
{
    __shared__ __align__(16) uint16_t QS[256][40];
    __shared__ __align__(16) uint16_t Ks[256][40];
    __shared__ __align__(16) uint16_t Vt[32][264];
    const int b = blockIdx.x >> 3, h = blockIdx.x & 7;
    const float l2g = sa.l2g[h];
    const int t = threadIdx.x, w = t >> 6, lane = t & 63, l16 = lane & 15, lg = lane >> 4;
    const size_t base = ((size_t)b * 256) * 256 + (size_t)h * 32;
    const uint16_t *q = sa.bq, *kbuf = sa.bk, *vbuf = sa.bv, *g = sa.bg;
    uint16_t* out = sa.brg;

    {
        const uint4* qr = (const uint4*)(q + base + (size_t)t * 256);
        *(uint4*)&QS[t][0] = qr[0]; *(uint4*)&QS[t][8] = qr[1];
        *(uint4*)&QS[t][16] = qr[2]; *(uint4*)&QS[t][24] = qr[3];
        const uint4* kr = (const uint4*)(kbuf + base + (size_t)t * 256);
        *(uint4*)&Ks[t][0] = kr[0]; *(uint4*)&Ks[t][8] = kr[1];
        *(uint4*)&Ks[t][16] = kr[2]; *(uint4*)&Ks[t][24] = kr[3];
        union { uint4 v4[4]; uint16_t u[32]; } vv;
        const uint4* vr = (const uint4*)(vbuf + base + (size_t)t * 256);
        vv.v4[0] = vr[0]; vv.v4[1] = vr[1]; vv.v4[2] = vr[2]; vv.v4[3] = vr[3];
#pragma unroll
        for (int d = 0; d < 32; ++d) Vt[d][t] = vv.u[d];
    }
    __syncthreads();

    short8 qF[4];
#pragma unroll
    for (int rt = 0; rt < 4; ++rt)
        qF[rt] = *(const short8*)&QS[(w << 6) + (rt << 4) + l16][lg << 3];

    floatx4 racc[4][2];
#pragma unroll
    for (int i = 0; i < 4; ++i) { racc[i][0] = (floatx4){0,0,0,0}; racc[i][1] = (floatx4){0,0,0,0}; }

    const float invsq = 0.17677669529663687f;
    for (int jt = 0; jt < 8; ++jt) {
        const int j0 = jt << 5;
        floatx4 sacc[4][2];
#pragma unroll
        for (int i = 0; i < 4; ++i) { sacc[i][0] = (floatx4){0,0,0,0}; sacc[i][1] = (floatx4){0,0,0,0}; }
        short8 kF[2];
#pragma unroll
        for (int ct = 0; ct < 2; ++ct)
            kF[ct] = *(const short8*)&Ks[j0 + (ct << 4) + l16][lg << 3];
#pragma unroll
        for (int rt = 0; rt < 4; ++rt)
#pragma unroll
            for (int ct = 0; ct < 2; ++ct)
                sacc[rt][ct] = __builtin_amdgcn_mfma_f32_16x16x32_bf16(
                    qF[rt], kF[ct], sacc[rt][ct], 0, 0, 0);
#pragma unroll
        for (int rt = 0; rt < 4; ++rt)
#pragma unroll
            for (int ct = 0; ct < 2; ++ct)
#pragma unroll
                for (int r = 0; r < 4; ++r) {
                    int row = (rt << 4) + (lg << 2) + r;
                    int i = (w << 6) + row;
                    int j = j0 + (ct << 4) + l16;
                    float svv = 0.f;
                    if (i >= j)
                        svv = sacc[rt][ct][r] * invsq *
                              exp2f((float)((i >> 3) - (j >> 3)) * l2g);
                    QS[(w << 6) + row][(ct << 4) + l16] = f2bf(svv);
                }
        short8 vF[2];
#pragma unroll
        for (int ct = 0; ct < 2; ++ct)
            vF[ct] = *(const short8*)&Vt[(ct << 4) + l16][j0 + (lg << 3)];
#pragma unroll
        for (int rt = 0; rt < 4; ++rt) {
            short8 sF = *(const short8*)&QS[(w << 6) + (rt << 4) + l16][lg << 3];
#pragma unroll
            for (int ct = 0; ct < 2; ++ct)
                racc[rt][ct] = __builtin_amdgcn_mfma_f32_16x16x32_bf16(
                    sF, vF[ct], racc[rt][ct], 0, 0, 0);
        }
    }

#pragma unroll
    for (int rt = 0; rt < 4; ++rt)
#pragma unroll
        for (int r = 0; r < 4; ++r) {
            float v0 = racc[rt][0][r], v1 = racc[rt][1][r];
            float s1 = v0 + v1, s2 = v0 * v0 + v1 * v1;
            s1 += __shfl_xor(s1, 1, 64); s2 += __shfl_xor(s2, 1, 64);
            s1 += __shfl_xor(s1, 2, 64); s2 += __shfl_xor(s2, 2, 64);
            s1 += __shfl_xor(s1, 4, 64); s2 += __shfl_xor(s2, 4, 64);
            s1 += __shfl_xor(s1, 8, 64); s2 += __shfl_xor(s2, 8, 64);
            float mu = s1 * (1.f / 32.f);
            float var = s2 * (1.f / 32.f) - mu * mu;
            float rstd = rsqrtf(var + 1e-5f);
            int srow = (w << 6) + (rt << 4) + (lg << 2) + r;
            size_t obase = ((size_t)b * 256 + srow) * 256 + (size_t)h * 32;
#pragma unroll
            for (int ct = 0; ct < 2; ++ct) {
                int d = (ct << 4) + l16;
                float x = ct ? v1 : v0;
                float y = (x - mu) * rstd * gns[h * 32 + d] + gnb[h * 32 + d];
                float gv = swishf(bf2f(g[obase + d]));
                out[obase + d] = f2bf(y * gv);
            }
        }
}

__global__ __launch_bounds__(256) void g1_k(SegArgs sa,
    const uint16_t* __restrict__ wo, const float* __restrict__ ln1,
    const uint16_t* __restrict__ wq, const uint16_t* __restrict__ wk,
    const uint16_t* __restrict__ wv, const uint16_t* __restrict__ wg)
{
    __shared__ float rowsum[4][32];
    const int m0 = blockIdx.x * 32;
    gemm_dev<EP_RESID_RMS, 256>(m0, sa.brg, wo, sa.xb, nullptr, sa.xf, ln1, sa.xf, rowsum, nullptr);
    gemm_dev<EP_NONE, 256>(m0, sa.xb,   wk, sa.bk, nullptr, nullptr, nullptr, nullptr, rowsum, nullptr);
    gemm_dev<EP_NONE, 256>(m0, sa.xb,   wv, sa.bv, nullptr, nullptr, nullptr, nullptr, rowsum, nullptr);
    gemm_dev<EP_NONE, 256>(m0, sa.obsb, wq, sa.bq, nullptr, nullptr, nullptr, nullptr, rowsum, nullptr);
    gemm_dev<EP_NONE, 256>(m0, sa.obsb, wg, sa.bg, nullptr, nullptr, nullptr, nullptr, rowsum, nullptr);
}

__global__ __launch_bounds__(256) void g2_k(SegArgs sa,
    const uint16_t* __restrict__ wo, const float* __restrict__ ln2,
    const uint16_t* __restrict__ wswg, const uint16_t* __restrict__ wsw1,
    const uint16_t* __restrict__ wsw2, const float* __restrict__ ln3,
    const uint16_t* __restrict__ nwq, const uint16_t* __restrict__ nwk,
    const uint16_t* __restrict__ nwv, const uint16_t* __restrict__ nwg)
{
    __shared__ float rowsum[4][32];
    const int m0 = blockIdx.x * 32;
    gemm_dev<EP_RESID_RMS, 256>(m0, sa.brg, wo, sa.xb, nullptr, sa.obs, ln2, sa.xf, rowsum, nullptr);
    {
        float sv[32];
        gemm_dev<EP_STASH, 256>(m0, sa.xb, wswg, nullptr, nullptr, nullptr, nullptr, nullptr, rowsum, sv);
        gemm_dev<EP_SWIMUL, 256>(m0, sa.xb, wsw1, sa.bk, nullptr, nullptr, nullptr, nullptr, rowsum, sv);
    }
    __syncthreads();
    gemm_dev<EP_RESID_RMS, 256>(m0, sa.bk, wsw2, sa.xb, nullptr, sa.xf, ln3, sa.xf, rowsum, nullptr);
    if (nwq) {
        gemm_dev<EP_NONE, 256>(m0, sa.xb, nwq, sa.bq, nullptr, nullptr, nullptr, nullptr, rowsum, nullptr);
        gemm_dev<EP_NONE, 256>(m0, sa.xb, nwk, sa.bk, nullptr, nullptr, nullptr, nullptr, rowsum, nullptr);
        gemm_dev<EP_NONE, 256>(m0, sa.xb, nwv, sa.bv, nullptr, nullptr, nullptr, nullptr, rowsum, nullptr);
        gemm_dev<EP_NONE, 256>(m0, sa.xb, nwg, sa.bg, nullptr, nullptr, nullptr, nullptr, rowsum, nullptr);
    }
}

__global__ __launch_bounds__(256) void head_k(SegArgs sa, const uint16_t* __restrict__ hw1t)
{
    __shared__ float rowsum[4][32];
    __shared__ float w2s[8192];
    const int t = threadIdx.x;
    const int m0 = blockIdx.x * 32;
    gemm_dev<EP_GELU_RMS, 256>(m0, sa.xb, hw1t, sa.bq, sa.hb1, nullptr, sa.hln,
                               nullptr, rowsum, nullptr);
    __syncthreads();
#pragma unroll
    for (int j = 0; j < 32; ++j) w2s[j * 256 + t] = sa.hw2[j * 256 + t];
    __syncthreads();
    {
        int n = t & 31, rs = t >> 5;
#pragma unroll
        for (int rr = 0; rr < 4; ++rr) {
            int row = m0 + (rr << 3) + rs;
            float a0 = sa.hb2[n];
#pragma unroll 8
            for (int kk = 0; kk < 256; ++kk)
                a0 += bf2f(sa.bq[(size_t)row * 256 + kk]) * w2s[kk * 32 + n];
            sa.outp[(size_t)row * 32 + n] = a0;
        }
    }
}

// ---------------- host ----------------
extern "C" void kernel_launch(void* const* d_in, const int* in_sizes, int n_in,
                              void* d_out, int out_size, void* d_ws, size_t ws_size,
                              hipStream_t stream)
{
    const float* action = (const float*)d_in[0];
    const float* obs    = (const float*)d_in[1];
    const float* w_enc  = (const float*)d_in[2];
    const float* ln0    = (const float*)d_in[3];
    const float* wq1 = (const float*)d_in[4];
    const float* wk1 = (const float*)d_in[5];
    const float* wv1 = (const float*)d_in[6];
    const float* wg1 = (const float*)d_in[7];
    const float* wo1 = (const float*)d_in[8];
    const float* gns1 = (const float*)d_in[9];
    const float* gnb1 = (const float*)d_in[10];
    const float* ln1  = (const float*)d_in[11];
    const float* wq2 = (const float*)d_in[12];
    const float* wk2 = (const float*)d_in[13];
    const float* wv2 = (const float*)d_in[14];
    const float* wg2 = (const float*)d_in[15];
    const float* wo2 = (const float*)d_in[16];
    const float* gns2 = (const float*)d_in[17];
    const float* gnb2 = (const float*)d_in[18];
    const float* ln2  = (const float*)d_in[19];
    const float* swgp = (const float*)d_in[20];
    const float* sw1p = (const float*)d_in[21];
    const float* sw2p = (const float*)d_in[22];
    const float* ln3  = (const float*)d_in[23];
    const float* hw1  = (const float*)d_in[24];
    const float* hb1  = (const float*)d_in[25];
    const float* hln  = (const float*)d_in[26];
    const float* hw2  = (const float*)d_in[27];
    const float* hb2  = (const float*)d_in[28];

    char* ws = (char*)d_ws;
    uint16_t* wt   = (uint16_t*)(ws + 0);
    uint16_t* actb = (uint16_t*)(ws + 6291456);
    uint16_t* obsb = (uint16_t*)(ws + 7340032);
    float*    xf   = (float*)   (ws + 15728640);
    uint16_t* xb   = (uint16_t*)(ws + 32505856);
    uint16_t* bq   = (uint16_t*)(ws + 40894464);
    uint16_t* bk   = (uint16_t*)(ws + 49283072);
    uint16_t* bv   = (uint16_t*)(ws + 57671680);
    uint16_t* bg   = (uint16_t*)(ws + 66060288);
    uint16_t* brg  = (uint16_t*)(ws + 74448896);

    uint16_t* wtenc = wt;
    uint16_t* hw1t  = wt + CHUNK_E + (size_t)39 * MAT_E;
    auto WTp = [&](int ti, int s) { return wt + CHUNK_E + (size_t)(ti * 3 + s) * MAT_E; };

    TArg ta;
    ta.src[0] = w_enc;
    ta.src[1] = wq1;  ta.src[2] = wk1;  ta.src[3] = wv1;  ta.src[4] = wg1;  ta.src[5] = wo1;
    ta.src[6] = wq2;  ta.src[7] = wk2;  ta.src[8] = wv2;  ta.src[9] = wg2;  ta.src[10] = wo2;
    ta.src[11] = swgp; ta.src[12] = sw1p; ta.src[13] = sw2p; ta.src[14] = hw1;
    tpose_k<<<dim3(4, 8, 41), 256, 0, stream>>>(ta, wt);

    SegArgs sa;
    sa.action = action; sa.obs = obs;
    sa.actb = actb; sa.obsb = obsb; sa.xb = xb;
    sa.bq = bq; sa.bk = bk; sa.bv = bv; sa.bg = bg; sa.brg = brg;
    sa.xf = xf;
    sa.ln0 = ln0; sa.hb1 = hb1; sa.hln = hln; sa.hw2 = hw2; sa.hb2 = hb2;
    sa.outp = (float*)d_out;
    {
        const double a = log(1.0 / 32.0), bb = log(1.0 / 512.0);
        for (int hh = 0; hh < 8; ++hh) {
            double lg = a + (bb - a) * hh / 7.0;
            double gam = 1.0 - exp(lg);
            sa.l2g[hh] = (float)(log(gam) / log(2.0));
        }
    }

    dim3 GB(512), TB(256);
    seg0_k<<<GB, TB, 0, stream>>>(sa, wtenc, WTp(0, 0), WTp(1, 0), WTp(2, 0), WTp(3, 0));
    for (int b3 = 0; b3 < 3; ++b3) {
        attn_k<<<GB, TB, 0, stream>>>(sa, gns1 + b3 * 256, gnb1 + b3 * 256);
        g1_k<<<GB, TB, 0, stream>>>(sa, WTp(4, b3), ln1 + b3 * 256,
                                    WTp(5, b3), WTp(6, b3), WTp(7, b3), WTp(8, b3));
        attn_k<<<GB, TB, 0, stream>>>(sa, gns2 + b3 * 256, gnb2 + b3 * 256);
        g2_k<<<GB, TB, 0, stream>>>(sa, WTp(9, b3), ln2 + b3 * 256,
                                    WTp(10, b3), WTp(11, b3), WTp(12, b3), ln3 + b3 * 256,
                                    b3 < 2 ? WTp(0, b3 + 1) : nullptr,
                                    b3 < 2 ? WTp(1, b3 + 1) : nullptr,
                                    b3 < 2 ? WTp(2, b3 + 1) : nullptr,
                                    b3 < 2 ? WTp(3, b3 + 1) : nullptr);
    }
    head_k<<<GB, TB, 0, stream>>>(sa, hw1t);
}

// Round 10
// 649.588 us; speedup vs baseline: 3.1661x; 1.1404x over previous
//
#include <hip/hip_runtime.h>
#include <cstdint>
#include <cmath>

typedef __attribute__((ext_vector_type(8))) short short8;
typedef __attribute__((ext_vector_type(4))) float floatx4;

#define DEV static __device__ __forceinline__

DEV float bf2f(uint16_t u) {
    union { uint32_t i; float f; } v; v.i = ((uint32_t)u) << 16; return v.f;
}
DEV uint16_t f2bf(float f) {
    union { float f; uint32_t i; } v; v.f = f;
    uint32_t r = (v.i + 0x7FFFu + ((v.i >> 16) & 1u)) >> 16;
    return (uint16_t)r;
}
DEV float swishf(float x) { return x / (1.f + __expf(-x)); }
DEV float geluf(float x) {
    const float c = 0.7978845608028654f;
    float t = tanhf(c * (x + 0.044715f * x * x * x));
    return 0.5f * x * (1.f + t);
}

#define CHUNK_E 8192
#define MAT_E   65536   // 8 chunks

// Block mapping (ALL segment kernels): batch b = blk & 63, slice/head s = blk >> 6.
// XCD id = blk % 8 = b % 8  ->  every producer/consumer of batch b shares one XCD,
// so inter-stage activations stay in that XCD's L2 instead of round-tripping HBM.

// ---- transpose+convert: W[K,N=256] fp32 -> packed chunks [kc][n][32] bf16 ----
struct TArg { const float* src[15]; };

__global__ __launch_bounds__(256) void tpose_k(TArg ta, uint16_t* __restrict__ arena) {
    int z = blockIdx.z;
    const float* src; uint16_t* dst;
    if (z == 0) {
        if (blockIdx.y) return;
        src = ta.src[0]; dst = arena;                            // w_enc [32,256]
    } else if (z <= 39) {
        int q = z - 1; int ti = q / 3, s = q % 3;
        src = ta.src[1 + ti] + (size_t)s * 65536;
        dst = arena + CHUNK_E + (size_t)(ti * 3 + s) * MAT_E;
    } else {
        src = ta.src[14]; dst = arena + CHUNK_E + (size_t)39 * MAT_E;   // hw1
    }
    int k0 = blockIdx.y << 5;
    int n0 = blockIdx.x << 6;
    __shared__ __align__(16) uint16_t tile[32][72];
    int t = threadIdx.x;
    {
        int r = t >> 3, c = (t & 7) << 3;
        const float* s0 = src + (size_t)(k0 + r) * 256 + n0 + c;
        float4 f0 = *(const float4*)s0;
        float4 f1 = *(const float4*)(s0 + 4);
        tile[r][c + 0] = f2bf(f0.x); tile[r][c + 1] = f2bf(f0.y);
        tile[r][c + 2] = f2bf(f0.z); tile[r][c + 3] = f2bf(f0.w);
        tile[r][c + 4] = f2bf(f1.x); tile[r][c + 5] = f2bf(f1.y);
        tile[r][c + 6] = f2bf(f1.z); tile[r][c + 7] = f2bf(f1.w);
    }
    __syncthreads();
    {
        int n = t >> 2, c = (t & 3) << 3;
        uint16_t tmp[8];
#pragma unroll
        for (int j = 0; j < 8; ++j) tmp[j] = tile[c + j][n];
        *(uint4*)&dst[(size_t)(k0 >> 5) * CHUNK_E + (size_t)(n0 + n) * 32 + c] = *(uint4*)tmp;
    }
}

// ---------------- shared pieces ----------------
struct SegArgs {
    const float* action; const float* obs;
    uint16_t *actb, *obsb, *xb, *bq, *bk, *bv, *bg, *brg;
    const float *ln0, *hb1, *hln, *hw2, *hb2;
    float* outp;
    float l2g[8];
};

enum { EP_NONE = 0, EP_GELU_RMS = 1, EP_RESID_RMS = 2, EP_STASH = 3, EP_SWIMUL = 4 };

// 32-row x 256-col GEMM tile, zero-LDS main loop. Block-local rows. bf16 residual.
template<int EPI, int K>
DEV void gemm_dev(int m0, const uint16_t* __restrict__ A, const uint16_t* __restrict__ Wt,
                  uint16_t* __restrict__ O, const float* __restrict__ bias,
                  const uint16_t* __restrict__ resid, const float* __restrict__ lnw,
                  float (&rowsum)[4][32], float* sv)
{
    const int t = threadIdx.x;
    const int w = t >> 6, lane = t & 63, l16 = lane & 15, lg = lane >> 4;
    constexpr int NC = K / 32;

    floatx4 acc[2][4];
#pragma unroll
    for (int i = 0; i < 2; ++i)
#pragma unroll
        for (int j = 0; j < 4; ++j) acc[i][j] = (floatx4){0.f, 0.f, 0.f, 0.f};

#pragma unroll
    for (int kc = 0; kc < NC; ++kc) {
        short8 aF[2], bF[4];
#pragma unroll
        for (int rt = 0; rt < 2; ++rt)
            aF[rt] = *(const short8*)(A + (size_t)(m0 + (rt << 4) + l16) * K +
                                      (kc << 5) + (lg << 3));
#pragma unroll
        for (int ct = 0; ct < 4; ++ct)
            bF[ct] = *(const short8*)(Wt + (size_t)kc * CHUNK_E +
                                      (size_t)((w << 6) + (ct << 4) + l16) * 32 + (lg << 3));
#pragma unroll
        for (int rt = 0; rt < 2; ++rt)
#pragma unroll
            for (int ct = 0; ct < 4; ++ct)
                acc[rt][ct] = __builtin_amdgcn_mfma_f32_16x16x32_bf16(
                    aF[rt], bF[ct], acc[rt][ct], 0, 0, 0);
    }

    if (EPI == EP_STASH) {
#pragma unroll
        for (int rt = 0; rt < 2; ++rt)
#pragma unroll
            for (int ct = 0; ct < 4; ++ct)
#pragma unroll
                for (int r = 0; r < 4; ++r)
                    sv[((rt << 2) + ct) * 4 + r] = acc[rt][ct][r];
        return;
    }

    float v[2][4][4];
#pragma unroll
    for (int rt = 0; rt < 2; ++rt)
#pragma unroll
        for (int ct = 0; ct < 4; ++ct)
#pragma unroll
            for (int r = 0; r < 4; ++r) {
                int row = (rt << 4) + (lg << 2) + r;
                int col = (w << 6) + (ct << 4) + l16;
                size_t idx = (size_t)(m0 + row) * 256 + col;
                float x = acc[rt][ct][r];
                if (EPI == EP_GELU_RMS) { if (bias) x += bias[col]; x = geluf(x); }
                if (EPI == EP_RESID_RMS) x += bf2f(resid[idx]);
                if (EPI == EP_SWIMUL) x *= swishf(sv[((rt << 2) + ct) * 4 + r]);
                v[rt][ct][r] = x;
            }

    if (EPI == EP_GELU_RMS || EPI == EP_RESID_RMS) {
#pragma unroll
        for (int rt = 0; rt < 2; ++rt)
#pragma unroll
            for (int r = 0; r < 4; ++r) {
                float p = 0.f;
#pragma unroll
                for (int ct = 0; ct < 4; ++ct) p += v[rt][ct][r] * v[rt][ct][r];
                p += __shfl_xor(p, 1, 64); p += __shfl_xor(p, 2, 64);
                p += __shfl_xor(p, 4, 64); p += __shfl_xor(p, 8, 64);
                int row = (rt << 4) + (lg << 2) + r;
                if (l16 == 0) rowsum[w][row] = p;
            }
        __syncthreads();
#pragma unroll
        for (int rt = 0; rt < 2; ++rt)
#pragma unroll
            for (int r = 0; r < 4; ++r) {
                int row = (rt << 4) + (lg << 2) + r;
                float tot = rowsum[0][row] + rowsum[1][row] + rowsum[2][row] + rowsum[3][row];
                float rn = rsqrtf(tot * (1.f / 256.f) + 1e-6f);
#pragma unroll
                for (int ct = 0; ct < 4; ++ct) {
                    int col = (w << 6) + (ct << 4) + l16;
                    size_t idx = (size_t)(m0 + row) * 256 + col;
                    O[idx] = f2bf(v[rt][ct][r] * rn * lnw[col]);
                }
            }
        __syncthreads();
    } else {
#pragma unroll
        for (int rt = 0; rt < 2; ++rt)
#pragma unroll
            for (int ct = 0; ct < 4; ++ct)
#pragma unroll
                for (int r = 0; r < 4; ++r) {
                    int row = (rt << 4) + (lg << 2) + r;
                    int col = (w << 6) + (ct << 4) + l16;
                    O[(size_t)(m0 + row) * 256 + col] = f2bf(v[rt][ct][r]);
                }
    }
}

DEV int rowbase(int blk) { return (blk & 63) * 256 + (blk >> 6) * 32; }

// ---------------- segment kernels (512 blocks each) ----------------

__global__ __launch_bounds__(256, 2) void seg0_k(SegArgs sa, const uint16_t* __restrict__ wenc,
                                                 const uint16_t* __restrict__ wq,
                                                 const uint16_t* __restrict__ wk,
                                                 const uint16_t* __restrict__ wv,
                                                 const uint16_t* __restrict__ wg)
{
    __shared__ float rowsum[4][32];
    const int t = threadIdx.x;
    const int m0 = rowbase(blockIdx.x);
    {
        int r = t >> 3, c = (t & 7) << 2;
        float4 f = *(const float4*)(sa.action + (size_t)(m0 + r) * 32 + c);
        uint16_t tmp[4] = { f2bf(f.x), f2bf(f.y), f2bf(f.z), f2bf(f.w) };
        *(uint2*)(sa.actb + (size_t)(m0 + r) * 32 + c) = *(uint2*)tmp;
    }
    {
        const float4* ob = (const float4*)sa.obs + (size_t)m0 * 64;
        uint2* od = (uint2*)sa.obsb + (size_t)m0 * 64;
#pragma unroll
        for (int j = 0; j < 8; ++j) {
            float4 f = ob[j * 256 + t];
            uint16_t tmp[4] = { f2bf(f.x), f2bf(f.y), f2bf(f.z), f2bf(f.w) };
            od[j * 256 + t] = *(uint2*)tmp;
        }
    }
    __syncthreads();
    gemm_dev<EP_GELU_RMS, 32>(m0, sa.actb, wenc, sa.xb, nullptr, nullptr, sa.ln0, rowsum, nullptr);
    gemm_dev<EP_NONE, 256>(m0, sa.xb, wq, sa.bq, nullptr, nullptr, nullptr, rowsum, nullptr);
    gemm_dev<EP_NONE, 256>(m0, sa.xb, wk, sa.bk, nullptr, nullptr, nullptr, rowsum, nullptr);
    gemm_dev<EP_NONE, 256>(m0, sa.xb, wv, sa.bv, nullptr, nullptr, nullptr, rowsum, nullptr);
    gemm_dev<EP_NONE, 256>(m0, sa.xb, wg, sa.bg, nullptr, nullptr, nullptr, rowsum, nullptr);
}

__global__ __launch_bounds__(256, 2) void attn_k(SegArgs sa, const float* __restrict__ gns,
                                                 const float* __restrict__ gnb)
{
    __shared__ __align__(16) uint16_t QS[256][40];
    __shared__ __align__(16) uint16_t Ks[256][40];
    __shared__ __align__(16) uint16_t Vt[32][264];
    const int b = blockIdx.x & 63, h = blockIdx.x >> 6;
    const float l2g = sa.l2g[h];
    const int t = threadIdx.x, w = t >> 6, lane = t & 63, l16 = lane & 15, lg = lane >> 4;
    const size_t base = ((size_t)b * 256) * 256 + (size_t)h * 32;
    const uint16_t *q = sa.bq, *kbuf = sa.bk, *vbuf = sa.bv, *g = sa.bg;
    uint16_t* out = sa.brg;

    {
        const uint4* qr = (const uint4*)(q + base + (size_t)t * 256);
        *(uint4*)&QS[t][0] = qr[0]; *(uint4*)&QS[t][8] = qr[1];
        *(uint4*)&QS[t][16] = qr[2]; *(uint4*)&QS[t][24] = qr[3];
        const uint4* kr = (const uint4*)(kbuf + base + (size_t)t * 256);
        *(uint4*)&Ks[t][0] = kr[0]; *(uint4*)&Ks[t][8] = kr[1];
        *(uint4*)&Ks[t][16] = kr[2]; *(uint4*)&Ks[t][24] = kr[3];
        union { uint4 v4[4]; uint16_t u[32]; } vv;
        const uint4* vr = (const uint4*)(vbuf + base + (size_t)t * 256);
        vv.v4[0] = vr[0]; vv.v4[1] = vr[1]; vv.v4[2] = vr[2]; vv.v4[3] = vr[3];
#pragma unroll
        for (int d = 0; d < 32; ++d) Vt[d][t] = vv.u[d];
    }
    __syncthreads();

    short8 qF[4];
#pragma unroll
    for (int rt = 0; rt < 4; ++rt)
        qF[rt] = *(const short8*)&QS[(w << 6) + (rt << 4) + l16][lg << 3];

    floatx4 racc[4][2];
#pragma unroll
    for (int i = 0; i < 4; ++i) { racc[i][0] = (floatx4){0,0,0,0}; racc[i][1] = (floatx4){0,0,0,0}; }

    const float invsq = 0.17677669529663687f;
    const int jtmax = 2 * w + 1;           // causal: wave w's rows end at w*64+63
    for (int jt = 0; jt <= jtmax; ++jt) {
        const int j0 = jt << 5;
        floatx4 sacc[4][2];
#pragma unroll
        for (int i = 0; i < 4; ++i) { sacc[i][0] = (floatx4){0,0,0,0}; sacc[i][1] = (floatx4){0,0,0,0}; }
        short8 kF[2];
#pragma unroll
        for (int ct = 0; ct < 2; ++ct)
            kF[ct] = *(const short8*)&Ks[j0 + (ct << 4) + l16][lg << 3];
#pragma unroll
        for (int rt = 0; rt < 4; ++rt)
#pragma unroll
            for (int ct = 0; ct < 2; ++ct)
                sacc[rt][ct] = __builtin_amdgcn_mfma_f32_16x16x32_bf16(
                    qF[rt], kF[ct], sacc[rt][ct], 0, 0, 0);
#pragma unroll
        for (int rt = 0; rt < 4; ++rt)
#pragma unroll
            for (int ct = 0; ct < 2; ++ct)
#pragma unroll
                for (int r = 0; r < 4; ++r) {
                    int row = (rt << 4) + (lg << 2) + r;
                    int i = (w << 6) + row;
                    int j = j0 + (ct << 4) + l16;
                    float svv = 0.f;
                    if (i >= j)
                        svv = sacc[rt][ct][r] * invsq *
                              exp2f((float)((i >> 3) - (j >> 3)) * l2g);
                    QS[(w << 6) + row][(ct << 4) + l16] = f2bf(svv);
                }
        short8 vF[2];
#pragma unroll
        for (int ct = 0; ct < 2; ++ct)
            vF[ct] = *(const short8*)&Vt[(ct << 4) + l16][j0 + (lg << 3)];
#pragma unroll
        for (int rt = 0; rt < 4; ++rt) {
            short8 sF = *(const short8*)&QS[(w << 6) + (rt << 4) + l16][lg << 3];
#pragma unroll
            for (int ct = 0; ct < 2; ++ct)
                racc[rt][ct] = __builtin_amdgcn_mfma_f32_16x16x32_bf16(
                    sF, vF[ct], racc[rt][ct], 0, 0, 0);
        }
    }

#pragma unroll
    for (int rt = 0; rt < 4; ++rt)
#pragma unroll
        for (int r = 0; r < 4; ++r) {
            float v0 = racc[rt][0][r], v1 = racc[rt][1][r];
            float s1 = v0 + v1, s2 = v0 * v0 + v1 * v1;
            s1 += __shfl_xor(s1, 1, 64); s2 += __shfl_xor(s2, 1, 64);
            s1 += __shfl_xor(s1, 2, 64); s2 += __shfl_xor(s2, 2, 64);
            s1 += __shfl_xor(s1, 4, 64); s2 += __shfl_xor(s2, 4, 64);
            s1 += __shfl_xor(s1, 8, 64); s2 += __shfl_xor(s2, 8, 64);
            float mu = s1 * (1.f / 32.f);
            float var = s2 * (1.f / 32.f) - mu * mu;
            float rstd = rsqrtf(var + 1e-5f);
            int srow = (w << 6) + (rt << 4) + (lg << 2) + r;
            size_t obase = ((size_t)b * 256 + srow) * 256 + (size_t)h * 32;
#pragma unroll
            for (int ct = 0; ct < 2; ++ct) {
                int d = (ct << 4) + l16;
                float x = ct ? v1 : v0;
                float y = (x - mu) * rstd * gns[h * 32 + d] + gnb[h * 32 + d];
                float gv = swishf(bf2f(g[obase + d]));
                out[obase + d] = f2bf(y * gv);
            }
        }
}

__global__ __launch_bounds__(256, 2) void g1_k(SegArgs sa,
    const uint16_t* __restrict__ wo, const float* __restrict__ ln1,
    const uint16_t* __restrict__ wq, const uint16_t* __restrict__ wk,
    const uint16_t* __restrict__ wv, const uint16_t* __restrict__ wg)
{
    __shared__ float rowsum[4][32];
    const int m0 = rowbase(blockIdx.x);
    gemm_dev<EP_RESID_RMS, 256>(m0, sa.brg, wo, sa.xb, nullptr, sa.xb, ln1, rowsum, nullptr);
    gemm_dev<EP_NONE, 256>(m0, sa.xb,   wk, sa.bk, nullptr, nullptr, nullptr, rowsum, nullptr);
    gemm_dev<EP_NONE, 256>(m0, sa.xb,   wv, sa.bv, nullptr, nullptr, nullptr, rowsum, nullptr);
    gemm_dev<EP_NONE, 256>(m0, sa.obsb, wq, sa.bq, nullptr, nullptr, nullptr, rowsum, nullptr);
    gemm_dev<EP_NONE, 256>(m0, sa.obsb, wg, sa.bg, nullptr, nullptr, nullptr, rowsum, nullptr);
}

__global__ __launch_bounds__(256, 2) void g2_k(SegArgs sa,
    const uint16_t* __restrict__ wo, const float* __restrict__ ln2,
    const uint16_t* __restrict__ wswg, const uint16_t* __restrict__ wsw1,
    const uint16_t* __restrict__ wsw2, const float* __restrict__ ln3,
    const uint16_t* __restrict__ nwq, const uint16_t* __restrict__ nwk,
    const uint16_t* __restrict__ nwv, const uint16_t* __restrict__ nwg)
{
    __shared__ float rowsum[4][32];
    const int m0 = rowbase(blockIdx.x);
    gemm_dev<EP_RESID_RMS, 256>(m0, sa.brg, wo, sa.xb, nullptr, sa.obsb, ln2, rowsum, nullptr);
    {
        float sv[32];
        gemm_dev<EP_STASH, 256>(m0, sa.xb, wswg, nullptr, nullptr, nullptr, nullptr, rowsum, sv);
        gemm_dev<EP_SWIMUL, 256>(m0, sa.xb, wsw1, sa.bk, nullptr, nullptr, nullptr, rowsum, sv);
    }
    __syncthreads();
    gemm_dev<EP_RESID_RMS, 256>(m0, sa.bk, wsw2, sa.xb, nullptr, sa.xb, ln3, rowsum, nullptr);
    if (nwq) {
        gemm_dev<EP_NONE, 256>(m0, sa.xb, nwq, sa.bq, nullptr, nullptr, nullptr, rowsum, nullptr);
        gemm_dev<EP_NONE, 256>(m0, sa.xb, nwk, sa.bk, nullptr, nullptr, nullptr, rowsum, nullptr);
        gemm_dev<EP_NONE, 256>(m0, sa.xb, nwv, sa.bv, nullptr, nullptr, nullptr, rowsum, nullptr);
        gemm_dev<EP_NONE, 256>(m0, sa.xb, nwg, sa.bg, nullptr, nullptr, nullptr, rowsum, nullptr);
    }
}

__global__ __launch_bounds__(256, 2) void head_k(SegArgs sa, const uint16_t* __restrict__ hw1t)
{
    __shared__ float rowsum[4][32];
    __shared__ float w2s[8192];
    const int t = threadIdx.x;
    const int m0 = rowbase(blockIdx.x);
    gemm_dev<EP_GELU_RMS, 256>(m0, sa.xb, hw1t, sa.bq, sa.hb1, nullptr, sa.hln, rowsum, nullptr);
    __syncthreads();
#pragma unroll
    for (int j = 0; j < 32; ++j) w2s[j * 256 + t] = sa.hw2[j * 256 + t];
    __syncthreads();
    {
        int n = t & 31, rs = t >> 5;
#pragma unroll
        for (int rr = 0; rr < 4; ++rr) {
            int row = m0 + (rr << 3) + rs;
            float a0 = sa.hb2[n];
#pragma unroll 8
            for (int kk = 0; kk < 256; ++kk)
                a0 += bf2f(sa.bq[(size_t)row * 256 + kk]) * w2s[kk * 32 + n];
            sa.outp[(size_t)row * 32 + n] = a0;
        }
    }
}

// ---------------- host ----------------
extern "C" void kernel_launch(void* const* d_in, const int* in_sizes, int n_in,
                              void* d_out, int out_size, void* d_ws, size_t ws_size,
                              hipStream_t stream)
{
    const float* action = (const float*)d_in[0];
    const float* obs    = (const float*)d_in[1];
    const float* w_enc  = (const float*)d_in[2];
    const float* ln0    = (const float*)d_in[3];
    const float* wq1 = (const float*)d_in[4];
    const float* wk1 = (const float*)d_in[5];
    const float* wv1 = (const float*)d_in[6];
    const float* wg1 = (const float*)d_in[7];
    const float* wo1 = (const float*)d_in[8];
    const float* gns1 = (const float*)d_in[9];
    const float* gnb1 = (const float*)d_in[10];
    const float* ln1  = (const float*)d_in[11];
    const float* wq2 = (const float*)d_in[12];
    const float* wk2 = (const float*)d_in[13];
    const float* wv2 = (const float*)d_in[14];
    const float* wg2 = (const float*)d_in[15];
    const float* wo2 = (const float*)d_in[16];
    const float* gns2 = (const float*)d_in[17];
    const float* gnb2 = (const float*)d_in[18];
    const float* ln2  = (const float*)d_in[19];
    const float* swgp = (const float*)d_in[20];
    const float* sw1p = (const float*)d_in[21];
    const float* sw2p = (const float*)d_in[22];
    const float* ln3  = (const float*)d_in[23];
    const float* hw1  = (const float*)d_in[24];
    const float* hb1  = (const float*)d_in[25];
    const float* hln  = (const float*)d_in[26];
    const float* hw2  = (const float*)d_in[27];
    const float* hb2  = (const float*)d_in[28];

    char* ws = (char*)d_ws;
    uint16_t* wt   = (uint16_t*)(ws + 0);
    uint16_t* actb = (uint16_t*)(ws + 6291456);
    uint16_t* obsb = (uint16_t*)(ws + 7340032);
    uint16_t* xb   = (uint16_t*)(ws + 15728640);
    uint16_t* bq   = (uint16_t*)(ws + 24117248);
    uint16_t* bk   = (uint16_t*)(ws + 32505856);
    uint16_t* bv   = (uint16_t*)(ws + 40894464);
    uint16_t* bg   = (uint16_t*)(ws + 49283072);
    uint16_t* brg  = (uint16_t*)(ws + 57671680);

    uint16_t* wtenc = wt;
    uint16_t* hw1t  = wt + CHUNK_E + (size_t)39 * MAT_E;
    auto WTp = [&](int ti, int s) { return wt + CHUNK_E + (size_t)(ti * 3 + s) * MAT_E; };

    TArg ta;
    ta.src[0] = w_enc;
    ta.src[1] = wq1;  ta.src[2] = wk1;  ta.src[3] = wv1;  ta.src[4] = wg1;  ta.src[5] = wo1;
    ta.src[6] = wq2;  ta.src[7] = wk2;  ta.src[8] = wv2;  ta.src[9] = wg2;  ta.src[10] = wo2;
    ta.src[11] = swgp; ta.src[12] = sw1p; ta.src[13] = sw2p; ta.src[14] = hw1;
    tpose_k<<<dim3(4, 8, 41), 256, 0, stream>>>(ta, wt);

    SegArgs sa;
    sa.action = action; sa.obs = obs;
    sa.actb = actb; sa.obsb = obsb; sa.xb = xb;
    sa.bq = bq; sa.bk = bk; sa.bv = bv; sa.bg = bg; sa.brg = brg;
    sa.ln0 = ln0; sa.hb1 = hb1; sa.hln = hln; sa.hw2 = hw2; sa.hb2 = hb2;
    sa.outp = (float*)d_out;
    {
        const double a = log(1.0 / 32.0), bb = log(1.0 / 512.0);
        for (int hh = 0; hh < 8; ++hh) {
            double lg = a + (bb - a) * hh / 7.0;
            double gam = 1.0 - exp(lg);
            sa.l2g[hh] = (float)(log(gam) / log(2.0));
        }
    }

    dim3 GB(512), TB(256);
    seg0_k<<<GB, TB, 0, stream>>>(sa, wtenc, WTp(0, 0), WTp(1, 0), WTp(2, 0), WTp(3, 0));
    for (int b3 = 0; b3 < 3; ++b3) {
        attn_k<<<GB, TB, 0, stream>>>(sa, gns1 + b3 * 256, gnb1 + b3 * 256);
        g1_k<<<GB, TB, 0, stream>>>(sa, WTp(4, b3), ln1 + b3 * 256,
                                    WTp(5, b3), WTp(6, b3), WTp(7, b3), WTp(8, b3));
        attn_k<<<GB, TB, 0, stream>>>(sa, gns2 + b3 * 256, gnb2 + b3 * 256);
        g2_k<<<GB, TB, 0, stream>>>(sa, WTp(9, b3), ln2 + b3 * 256,
                                    WTp(10, b3), WTp(11, b3), WTp(12, b3), ln3 + b3 * 256,
                                    b3 < 2 ? WTp(0, b3 + 1) : nullptr,
                                    b3 < 2 ? WTp(1, b3 + 1) : nullptr,
                                    b3 < 2 ? WTp(2, b3 + 1) : nullptr,
                                    b3 < 2 ? WTp(3, b3 + 1) : nullptr);
    }
    head_k<<<GB, TB, 0, stream>>>(sa, hw1t);
}

// Round 12
// 605.497 us; speedup vs baseline: 3.3967x; 1.0728x over previous
//
#include <hip/hip_runtime.h>
#include <cstdint>
#include <cmath>

typedef __attribute__((ext_vector_type(8))) short short8;
typedef __attribute__((ext_vector_type(4))) float floatx4;

#define DEV static __device__ __forceinline__

DEV float bf2f(uint16_t u) {
    union { uint32_t i; float f; } v; v.i = ((uint32_t)u) << 16; return v.f;
}
DEV uint16_t f2bf(float f) {
    union { float f; uint32_t i; } v; v.f = f;
    uint32_t r = (v.i + 0x7FFFu + ((v.i >> 16) & 1u)) >> 16;
    return (uint16_t)r;
}
DEV float swishf(float x) { return x / (1.f + __expf(-x)); }
DEV float geluf(float x) {
    const float c = 0.7978845608028654f;
    float t = tanhf(c * (x + 0.044715f * x * x * x));
    return 0.5f * x * (1.f + t);
}

#define CHUNK_E 8192
#define MAT_E   65536   // 8 chunks

// Block mapping (ALL segment kernels): batch b = blk & 63, slice/head s = blk >> 6.
// XCD id = blk % 8 = b % 8  ->  every producer/consumer of batch b shares one XCD.

// ---- transpose+convert: W[K,N=256] fp32 -> packed chunks [kc][n][32] bf16 ----
struct TArg { const float* src[15]; };

__global__ __launch_bounds__(256) void tpose_k(TArg ta, uint16_t* __restrict__ arena) {
    int z = blockIdx.z;
    const float* src; uint16_t* dst;
    if (z == 0) {
        if (blockIdx.y) return;
        src = ta.src[0]; dst = arena;                            // w_enc [32,256]
    } else if (z <= 39) {
        int q = z - 1; int ti = q / 3, s = q % 3;
        src = ta.src[1 + ti] + (size_t)s * 65536;
        dst = arena + CHUNK_E + (size_t)(ti * 3 + s) * MAT_E;
    } else {
        src = ta.src[14]; dst = arena + CHUNK_E + (size_t)39 * MAT_E;   // hw1
    }
    int k0 = blockIdx.y << 5;
    int n0 = blockIdx.x << 6;
    __shared__ __align__(16) uint16_t tile[32][72];
    int t = threadIdx.x;
    {
        int r = t >> 3, c = (t & 7) << 3;
        const float* s0 = src + (size_t)(k0 + r) * 256 + n0 + c;
        float4 f0 = *(const float4*)s0;
        float4 f1 = *(const float4*)(s0 + 4);
        tile[r][c + 0] = f2bf(f0.x); tile[r][c + 1] = f2bf(f0.y);
        tile[r][c + 2] = f2bf(f0.z); tile[r][c + 3] = f2bf(f0.w);
        tile[r][c + 4] = f2bf(f1.x); tile[r][c + 5] = f2bf(f1.y);
        tile[r][c + 6] = f2bf(f1.z); tile[r][c + 7] = f2bf(f1.w);
    }
    __syncthreads();
    {
        int n = t >> 2, c = (t & 3) << 3;
        uint16_t tmp[8];
#pragma unroll
        for (int j = 0; j < 8; ++j) tmp[j] = tile[c + j][n];
        *(uint4*)&dst[(size_t)(k0 >> 5) * CHUNK_E + (size_t)(n0 + n) * 32 + c] = *(uint4*)tmp;
    }
}

// ---------------- shared pieces ----------------
struct SegArgs {
    const float* action; const float* obs;
    uint16_t *actb, *obsb, *xb, *bq, *bk, *bv, *bg, *brg;
    const float *ln0, *hb1, *hln, *hw2, *hb2;
    float* outp;
    float l2g[8];
};

enum { EP_NONE = 0, EP_GELU_RMS = 1, EP_RESID_RMS = 2 };
enum { EP2_NONE = 0, EP2_SWIGLU = 1 };

// ---- single GEMM: 32-row x 256-col tile, zero-LDS, bf16 residual ----
template<int EPI, int K>
DEV void gemm_dev(int m0, const uint16_t* __restrict__ A, const uint16_t* __restrict__ Wt,
                  uint16_t* __restrict__ O, const float* __restrict__ bias,
                  const uint16_t* __restrict__ resid, const float* __restrict__ lnw,
                  float (&rowsum)[4][32])
{
    const int t = threadIdx.x;
    const int w = t >> 6, lane = t & 63, l16 = lane & 15, lg = lane >> 4;
    constexpr int NC = K / 32;

    floatx4 acc[2][4];
#pragma unroll
    for (int i = 0; i < 2; ++i)
#pragma unroll
        for (int j = 0; j < 4; ++j) acc[i][j] = (floatx4){0.f, 0.f, 0.f, 0.f};

#pragma unroll
    for (int kc = 0; kc < NC; ++kc) {
        short8 aF[2], bF[4];
#pragma unroll
        for (int rt = 0; rt < 2; ++rt)
            aF[rt] = *(const short8*)(A + (size_t)(m0 + (rt << 4) + l16) * K +
                                      (kc << 5) + (lg << 3));
#pragma unroll
        for (int ct = 0; ct < 4; ++ct)
            bF[ct] = *(const short8*)(Wt + (size_t)kc * CHUNK_E +
                                      (size_t)((w << 6) + (ct << 4) + l16) * 32 + (lg << 3));
#pragma unroll
        for (int rt = 0; rt < 2; ++rt)
#pragma unroll
            for (int ct = 0; ct < 4; ++ct)
                acc[rt][ct] = __builtin_amdgcn_mfma_f32_16x16x32_bf16(
                    aF[rt], bF[ct], acc[rt][ct], 0, 0, 0);
    }

    float v[2][4][4];
#pragma unroll
    for (int rt = 0; rt < 2; ++rt)
#pragma unroll
        for (int ct = 0; ct < 4; ++ct)
#pragma unroll
            for (int r = 0; r < 4; ++r) {
                int row = (rt << 4) + (lg << 2) + r;
                int col = (w << 6) + (ct << 4) + l16;
                size_t idx = (size_t)(m0 + row) * 256 + col;
                float x = acc[rt][ct][r];
                if (EPI == EP_GELU_RMS) { if (bias) x += bias[col]; x = geluf(x); }
                if (EPI == EP_RESID_RMS) x += bf2f(resid[idx]);
                v[rt][ct][r] = x;
            }

    if (EPI == EP_GELU_RMS || EPI == EP_RESID_RMS) {
#pragma unroll
        for (int rt = 0; rt < 2; ++rt)
#pragma unroll
            for (int r = 0; r < 4; ++r) {
                float p = 0.f;
#pragma unroll
                for (int ct = 0; ct < 4; ++ct) p += v[rt][ct][r] * v[rt][ct][r];
                p += __shfl_xor(p, 1, 64); p += __shfl_xor(p, 2, 64);
                p += __shfl_xor(p, 4, 64); p += __shfl_xor(p, 8, 64);
                int row = (rt << 4) + (lg << 2) + r;
                if (l16 == 0) rowsum[w][row] = p;
            }
        __syncthreads();
#pragma unroll
        for (int rt = 0; rt < 2; ++rt)
#pragma unroll
            for (int r = 0; r < 4; ++r) {
                int row = (rt << 4) + (lg << 2) + r;
                float tot = rowsum[0][row] + rowsum[1][row] + rowsum[2][row] + rowsum[3][row];
                float rn = rsqrtf(tot * (1.f / 256.f) + 1e-6f);
#pragma unroll
                for (int ct = 0; ct < 4; ++ct) {
                    int col = (w << 6) + (ct << 4) + l16;
                    size_t idx = (size_t)(m0 + row) * 256 + col;
                    O[idx] = f2bf(v[rt][ct][r] * rn * lnw[col]);
                }
            }
        __syncthreads();
    } else {
#pragma unroll
        for (int rt = 0; rt < 2; ++rt)
#pragma unroll
            for (int ct = 0; ct < 4; ++ct)
#pragma unroll
                for (int r = 0; r < 4; ++r) {
                    int row = (rt << 4) + (lg << 2) + r;
                    int col = (w << 6) + (ct << 4) + l16;
                    O[(size_t)(m0 + row) * 256 + col] = f2bf(v[rt][ct][r]);
                }
    }
}

// ---- dual GEMM: two weight matrices, SHARED A -> 16 MFMA per 10 loads, 2x ILP ----
// NOTE: no end-of-call barrier. If a later op in the SAME kernel reads the
// outputs as A (cross-wave columns), the caller MUST __syncthreads() first.
template<int EPI>
DEV void gemm2_dev(int m0, const uint16_t* __restrict__ A,
                   const uint16_t* __restrict__ W1, const uint16_t* __restrict__ W2,
                   uint16_t* __restrict__ O1, uint16_t* __restrict__ O2)
{
    const int t = threadIdx.x;
    const int w = t >> 6, lane = t & 63, l16 = lane & 15, lg = lane >> 4;

    floatx4 a1[2][4], a2[2][4];
#pragma unroll
    for (int i = 0; i < 2; ++i)
#pragma unroll
        for (int j = 0; j < 4; ++j) {
            a1[i][j] = (floatx4){0.f, 0.f, 0.f, 0.f};
            a2[i][j] = (floatx4){0.f, 0.f, 0.f, 0.f};
        }

#pragma unroll
    for (int kc = 0; kc < 8; ++kc) {
        short8 aF[2], b1[4], b2[4];
#pragma unroll
        for (int rt = 0; rt < 2; ++rt)
            aF[rt] = *(const short8*)(A + (size_t)(m0 + (rt << 4) + l16) * 256 +
                                      (kc << 5) + (lg << 3));
        size_t woff = (size_t)kc * CHUNK_E + (size_t)((w << 6) + l16) * 32 + (lg << 3);
#pragma unroll
        for (int ct = 0; ct < 4; ++ct) {
            b1[ct] = *(const short8*)(W1 + woff + (size_t)(ct << 4) * 32);
            b2[ct] = *(const short8*)(W2 + woff + (size_t)(ct << 4) * 32);
        }
#pragma unroll
        for (int rt = 0; rt < 2; ++rt)
#pragma unroll
            for (int ct = 0; ct < 4; ++ct) {
                a1[rt][ct] = __builtin_amdgcn_mfma_f32_16x16x32_bf16(aF[rt], b1[ct], a1[rt][ct], 0, 0, 0);
                a2[rt][ct] = __builtin_amdgcn_mfma_f32_16x16x32_bf16(aF[rt], b2[ct], a2[rt][ct], 0, 0, 0);
            }
    }

#pragma unroll
    for (int rt = 0; rt < 2; ++rt)
#pragma unroll
        for (int ct = 0; ct < 4; ++ct)
#pragma unroll
            for (int r = 0; r < 4; ++r) {
                int row = (rt << 4) + (lg << 2) + r;
                int col = (w << 6) + (ct << 4) + l16;
                size_t idx = (size_t)(m0 + row) * 256 + col;
                if (EPI == EP2_NONE) {
                    O1[idx] = f2bf(a1[rt][ct][r]);
                    O2[idx] = f2bf(a2[rt][ct][r]);
                } else {  // EP2_SWIGLU: swish(gate)*up
                    O1[idx] = f2bf(swishf(a1[rt][ct][r]) * a2[rt][ct][r]);
                }
            }
}

DEV int rowbase(int blk) { return (blk & 63) * 256 + (blk >> 6) * 32; }

// ---------------- segment kernels (512 blocks each) ----------------

__global__ __launch_bounds__(256, 2) void seg0_k(SegArgs sa, const uint16_t* __restrict__ wenc,
                                                 const uint16_t* __restrict__ wq,
                                                 const uint16_t* __restrict__ wk,
                                                 const uint16_t* __restrict__ wv,
                                                 const uint16_t* __restrict__ wg)
{
    __shared__ float rowsum[4][32];
    const int t = threadIdx.x;
    const int m0 = rowbase(blockIdx.x);
    {
        int r = t >> 3, c = (t & 7) << 2;
        float4 f = *(const float4*)(sa.action + (size_t)(m0 + r) * 32 + c);
        uint16_t tmp[4] = { f2bf(f.x), f2bf(f.y), f2bf(f.z), f2bf(f.w) };
        *(uint2*)(sa.actb + (size_t)(m0 + r) * 32 + c) = *(uint2*)tmp;
    }
    {
        const float4* ob = (const float4*)sa.obs + (size_t)m0 * 64;
        uint2* od = (uint2*)sa.obsb + (size_t)m0 * 64;
#pragma unroll
        for (int j = 0; j < 8; ++j) {
            float4 f = ob[j * 256 + t];
            uint16_t tmp[4] = { f2bf(f.x), f2bf(f.y), f2bf(f.z), f2bf(f.w) };
            od[j * 256 + t] = *(uint2*)tmp;
        }
    }
    __syncthreads();
    gemm_dev<EP_GELU_RMS, 32>(m0, sa.actb, wenc, sa.xb, nullptr, nullptr, sa.ln0, rowsum);
    gemm2_dev<EP2_NONE>(m0, sa.xb, wq, wk, sa.bq, sa.bk);
    gemm2_dev<EP2_NONE>(m0, sa.xb, wv, wg, sa.bv, sa.bg);
}

__global__ __launch_bounds__(256, 2) void attn_k(SegArgs sa, const float* __restrict__ gns,
                                                 const float* __restrict__ gnb)
{
    __shared__ __align__(16) uint16_t QS[256][40];
    __shared__ __align__(16) uint16_t Ks[256][40];
    __shared__ __align__(16) uint16_t Vt[32][264];
    const int b = blockIdx.x & 63, h = blockIdx.x >> 6;
    const float l2g = sa.l2g[h];
    const int t = threadIdx.x, w = t >> 6, lane = t & 63, l16 = lane & 15, lg = lane >> 4;
    const size_t base = ((size_t)b * 256) * 256 + (size_t)h * 32;
    const uint16_t *q = sa.bq, *kbuf = sa.bk, *vbuf = sa.bv, *g = sa.bg;
    uint16_t* out = sa.brg;

    {
        const uint4* qr = (const uint4*)(q + base + (size_t)t * 256);
        *(uint4*)&QS[t][0] = qr[0]; *(uint4*)&QS[t][8] = qr[1];
        *(uint4*)&QS[t][16] = qr[2]; *(uint4*)&QS[t][24] = qr[3];
        const uint4* kr = (const uint4*)(kbuf + base + (size_t)t * 256);
        *(uint4*)&Ks[t][0] = kr[0]; *(uint4*)&Ks[t][8] = kr[1];
        *(uint4*)&Ks[t][16] = kr[2]; *(uint4*)&Ks[t][24] = kr[3];
        union { uint4 v4[4]; uint16_t u[32]; } vv;
        const uint4* vr = (const uint4*)(vbuf + base + (size_t)t * 256);
        vv.v4[0] = vr[0]; vv.v4[1] = vr[1]; vv.v4[2] = vr[2]; vv.v4[3] = vr[3];
#pragma unroll
        for (int d = 0; d < 32; ++d) Vt[d][t] = vv.u[d];
    }
    __syncthreads();

    short8 qF[4];
#pragma unroll
    for (int rt = 0; rt < 4; ++rt)
        qF[rt] = *(const short8*)&QS[(w << 6) + (rt << 4) + l16][lg << 3];

    floatx4 racc[4][2];
#pragma unroll
    for (int i = 0; i < 4; ++i) { racc[i][0] = (floatx4){0,0,0,0}; racc[i][1] = (floatx4){0,0,0,0}; }

    const float invsq = 0.17677669529663687f;
    const int jtmax = 2 * w + 1;           // causal trim
    for (int jt = 0; jt <= jtmax; ++jt) {
        const int j0 = jt << 5;
        floatx4 sacc[4][2];
#pragma unroll
        for (int i = 0; i < 4; ++i) { sacc[i][0] = (floatx4){0,0,0,0}; sacc[i][1] = (floatx4){0,0,0,0}; }
        short8 kF[2];
#pragma unroll
        for (int ct = 0; ct < 2; ++ct)
            kF[ct] = *(const short8*)&Ks[j0 + (ct << 4) + l16][lg << 3];
#pragma unroll
        for (int rt = 0; rt < 4; ++rt)
#pragma unroll
            for (int ct = 0; ct < 2; ++ct)
                sacc[rt][ct] = __builtin_amdgcn_mfma_f32_16x16x32_bf16(
                    qF[rt], kF[ct], sacc[rt][ct], 0, 0, 0);
#pragma unroll
        for (int rt = 0; rt < 4; ++rt)
#pragma unroll
            for (int ct = 0; ct < 2; ++ct)
#pragma unroll
                for (int r = 0; r < 4; ++r) {
                    int row = (rt << 4) + (lg << 2) + r;
                    int i = (w << 6) + row;
                    int j = j0 + (ct << 4) + l16;
                    float svv = 0.f;
                    if (i >= j)
                        svv = sacc[rt][ct][r] * invsq *
                              exp2f((float)((i >> 3) - (j >> 3)) * l2g);
                    QS[(w << 6) + row][(ct << 4) + l16] = f2bf(svv);
                }
        short8 vF[2];
#pragma unroll
        for (int ct = 0; ct < 2; ++ct)
            vF[ct] = *(const short8*)&Vt[(ct << 4) + l16][j0 + (lg << 3)];
#pragma unroll
        for (int rt = 0; rt < 4; ++rt) {
            short8 sF = *(const short8*)&QS[(w << 6) + (rt << 4) + l16][lg << 3];
#pragma unroll
            for (int ct = 0; ct < 2; ++ct)
                racc[rt][ct] = __builtin_amdgcn_mfma_f32_16x16x32_bf16(
                    sF, vF[ct], racc[rt][ct], 0, 0, 0);
        }
    }

#pragma unroll
    for (int rt = 0; rt < 4; ++rt)
#pragma unroll
        for (int r = 0; r < 4; ++r) {
            float v0 = racc[rt][0][r], v1 = racc[rt][1][r];
            float s1 = v0 + v1, s2 = v0 * v0 + v1 * v1;
            s1 += __shfl_xor(s1, 1, 64); s2 += __shfl_xor(s2, 1, 64);
            s1 += __shfl_xor(s1, 2, 64); s2 += __shfl_xor(s2, 2, 64);
            s1 += __shfl_xor(s1, 4, 64); s2 += __shfl_xor(s2, 4, 64);
            s1 += __shfl_xor(s1, 8, 64); s2 += __shfl_xor(s2, 8, 64);
            float mu = s1 * (1.f / 32.f);
            float var = s2 * (1.f / 32.f) - mu * mu;
            float rstd = rsqrtf(var + 1e-5f);
            int srow = (w << 6) + (rt << 4) + (lg << 2) + r;
            size_t obase = ((size_t)b * 256 + srow) * 256 + (size_t)h * 32;
#pragma unroll
            for (int ct = 0; ct < 2; ++ct) {
                int d = (ct << 4) + l16;
                float x = ct ? v1 : v0;
                float y = (x - mu) * rstd * gns[h * 32 + d] + gnb[h * 32 + d];
                float gv = swishf(bf2f(g[obase + d]));
                out[obase + d] = f2bf(y * gv);
            }
        }
}

__global__ __launch_bounds__(256, 2) void g1_k(SegArgs sa,
    const uint16_t* __restrict__ wo, const float* __restrict__ ln1,
    const uint16_t* __restrict__ wq, const uint16_t* __restrict__ wk,
    const uint16_t* __restrict__ wv, const uint16_t* __restrict__ wg)
{
    __shared__ float rowsum[4][32];
    const int m0 = rowbase(blockIdx.x);
    gemm_dev<EP_RESID_RMS, 256>(m0, sa.brg, wo, sa.xb, nullptr, sa.xb, ln1, rowsum);
    gemm2_dev<EP2_NONE>(m0, sa.xb,   wk, wv, sa.bk, sa.bv);
    gemm2_dev<EP2_NONE>(m0, sa.obsb, wq, wg, sa.bq, sa.bg);
}

__global__ __launch_bounds__(256, 2) void g2_k(SegArgs sa,
    const uint16_t* __restrict__ wo, const float* __restrict__ ln2,
    const uint16_t* __restrict__ wswg, const uint16_t* __restrict__ wsw1,
    const uint16_t* __restrict__ wsw2, const float* __restrict__ ln3,
    const uint16_t* __restrict__ nwq, const uint16_t* __restrict__ nwk,
    const uint16_t* __restrict__ nwv, const uint16_t* __restrict__ nwg)
{
    __shared__ float rowsum[4][32];
    const int m0 = rowbase(blockIdx.x);
    gemm_dev<EP_RESID_RMS, 256>(m0, sa.brg, wo, sa.xb, nullptr, sa.obsb, ln2, rowsum);
    gemm2_dev<EP2_SWIGLU>(m0, sa.xb, wswg, wsw1, sa.bk, nullptr);
    __syncthreads();   // RAW fix: bk written per-wave-column, read cross-wave as A below
    gemm_dev<EP_RESID_RMS, 256>(m0, sa.bk, wsw2, sa.xb, nullptr, sa.xb, ln3, rowsum);
    if (nwq) {
        gemm2_dev<EP2_NONE>(m0, sa.xb, nwq, nwk, sa.bq, sa.bk);
        gemm2_dev<EP2_NONE>(m0, sa.xb, nwv, nwg, sa.bv, sa.bg);
    }
}

__global__ __launch_bounds__(256, 2) void head_k(SegArgs sa, const uint16_t* __restrict__ hw1t)
{
    __shared__ float rowsum[4][32];
    __shared__ float w2s[8192];
    const int t = threadIdx.x;
    const int m0 = rowbase(blockIdx.x);
    gemm_dev<EP_GELU_RMS, 256>(m0, sa.xb, hw1t, sa.bq, sa.hb1, nullptr, sa.hln, rowsum);
    __syncthreads();
#pragma unroll
    for (int j = 0; j < 32; ++j) w2s[j * 256 + t] = sa.hw2[j * 256 + t];
    __syncthreads();
    {
        int n = t & 31, rs = t >> 5;
#pragma unroll
        for (int rr = 0; rr < 4; ++rr) {
            int row = m0 + (rr << 3) + rs;
            float a0 = sa.hb2[n];
#pragma unroll 8
            for (int kk = 0; kk < 256; ++kk)
                a0 += bf2f(sa.bq[(size_t)row * 256 + kk]) * w2s[kk * 32 + n];
            sa.outp[(size_t)row * 32 + n] = a0;
        }
    }
}

// ---------------- host ----------------
extern "C" void kernel_launch(void* const* d_in, const int* in_sizes, int n_in,
                              void* d_out, int out_size, void* d_ws, size_t ws_size,
                              hipStream_t stream)
{
    const float* action = (const float*)d_in[0];
    const float* obs    = (const float*)d_in[1];
    const float* w_enc  = (const float*)d_in[2];
    const float* ln0    = (const float*)d_in[3];
    const float* wq1 = (const float*)d_in[4];
    const float* wk1 = (const float*)d_in[5];
    const float* wv1 = (const float*)d_in[6];
    const float* wg1 = (const float*)d_in[7];
    const float* wo1 = (const float*)d_in[8];
    const float* gns1 = (const float*)d_in[9];
    const float* gnb1 = (const float*)d_in[10];
    const float* ln1  = (const float*)d_in[11];
    const float* wq2 = (const float*)d_in[12];
    const float* wk2 = (const float*)d_in[13];
    const float* wv2 = (const float*)d_in[14];
    const float* wg2 = (const float*)d_in[15];
    const float* wo2 = (const float*)d_in[16];
    const float* gns2 = (const float*)d_in[17];
    const float* gnb2 = (const float*)d_in[18];
    const float* ln2  = (const float*)d_in[19];
    const float* swgp = (const float*)d_in[20];
    const float* sw1p = (const float*)d_in[21];
    const float* sw2p = (const float*)d_in[22];
    const float* ln3  = (const float*)d_in[23];
    const float* hw1  = (const float*)d_in[24];
    const float* hb1  = (const float*)d_in[25];
    const float* hln  = (const float*)d_in[26];
    const float* hw2  = (const float*)d_in[27];
    const float* hb2  = (const float*)d_in[28];

    char* ws = (char*)d_ws;
    uint16_t* wt   = (uint16_t*)(ws + 0);
    uint16_t* actb = (uint16_t*)(ws + 6291456);
    uint16_t* obsb = (uint16_t*)(ws + 7340032);
    uint16_t* xb   = (uint16_t*)(ws + 15728640);
    uint16_t* bq   = (uint16_t*)(ws + 24117248);
    uint16_t* bk   = (uint16_t*)(ws + 32505856);
    uint16_t* bv   = (uint16_t*)(ws + 40894464);
    uint16_t* bg   = (uint16_t*)(ws + 49283072);
    uint16_t* brg  = (uint16_t*)(ws + 57671680);

    uint16_t* wtenc = wt;
    uint16_t* hw1t  = wt + CHUNK_E + (size_t)39 * MAT_E;
    auto WTp = [&](int ti, int s) { return wt + CHUNK_E + (size_t)(ti * 3 + s) * MAT_E; };

    TArg ta;
    ta.src[0] = w_enc;
    ta.src[1] = wq1;  ta.src[2] = wk1;  ta.src[3] = wv1;  ta.src[4] = wg1;  ta.src[5] = wo1;
    ta.src[6] = wq2;  ta.src[7] = wk2;  ta.src[8] = wv2;  ta.src[9] = wg2;  ta.src[10] = wo2;
    ta.src[11] = swgp; ta.src[12] = sw1p; ta.src[13] = sw2p; ta.src[14] = hw1;
    tpose_k<<<dim3(4, 8, 41), 256, 0, stream>>>(ta, wt);

    SegArgs sa;
    sa.action = action; sa.obs = obs;
    sa.actb = actb; sa.obsb = obsb; sa.xb = xb;
    sa.bq = bq; sa.bk = bk; sa.bv = bv; sa.bg = bg; sa.brg = brg;
    sa.ln0 = ln0; sa.hb1 = hb1; sa.hln = hln; sa.hw2 = hw2; sa.hb2 = hb2;
    sa.outp = (float*)d_out;
    {
        const double a = log(1.0 / 32.0), bb = log(1.0 / 512.0);
        for (int hh = 0; hh < 8; ++hh) {
            double lg = a + (bb - a) * hh / 7.0;
            double gam = 1.0 - exp(lg);
            sa.l2g[hh] = (float)(log(gam) / log(2.0));
        }
    }

    dim3 GB(512), TB(256);
    seg0_k<<<GB, TB, 0, stream>>>(sa, wtenc, WTp(0, 0), WTp(1, 0), WTp(2, 0), WTp(3, 0));
    for (int b3 = 0; b3 < 3; ++b3) {
        attn_k<<<GB, TB, 0, stream>>>(sa, gns1 + b3 * 256, gnb1 + b3 * 256);
        g1_k<<<GB, TB, 0, stream>>>(sa, WTp(4, b3), ln1 + b3 * 256,
                                    WTp(5, b3), WTp(6, b3), WTp(7, b3), WTp(8, b3));
        attn_k<<<GB, TB, 0, stream>>>(sa, gns2 + b3 * 256, gnb2 + b3 * 256);
        g2_k<<<GB, TB, 0, stream>>>(sa, WTp(9, b3), ln2 + b3 * 256,
                                    WTp(10, b3), WTp(11, b3), WTp(12, b3), ln3 + b3 * 256,
                                    b3 < 2 ? WTp(0, b3 + 1) : nullptr,
                                    b3 < 2 ? WTp(1, b3 + 1) : nullptr,
                                    b3 < 2 ? WTp(2, b3 + 1) : nullptr,
                                    b3 < 2 ? WTp(3, b3 + 1) : nullptr);
    }
    head_k<<<GB, TB, 0, stream>>>(sa, hw1t);
}